// Round 1
// 847.966 us; speedup vs baseline: 1.0006x; 1.0006x over previous
//
#include <hip/hip_runtime.h>
#include <hip/hip_bf16.h>
#include <cstdint>

// CLAM-MIL forward. Inputs/outputs FLOAT32; internal compute bf16 MFMA + fp32 accum.
// B=8, N=10000 (M=80000 rows), F=1024, Z=512, C=4.
//
// Round 6: latency + atomics fix.
//  - Both GEMMs: 2-phase double-buffered pipeline (stage step s+1 BEFORE computing
//    step s, single __syncthreads per step) -> staging latency hides under MFMA.
//    LDS 96KB/block (2 x 48KB buffers), 1 block/CU, 8 waves.
//  - gemm_gate: one block owns a full 128-row m-tile and loops the 4 n-chunks
//    internally; logits accumulated in registers (pc) across chunks and written
//    ONCE per row -> no device-scope atomics (WRITE_SIZE was 80 MB of 128B RMWs),
//    emb fetched once per m-tile.
//  - gemm_enc: n-halves looped in-block -> bags (328 MB f32) fetched once; f32
//    A staging split into load-early (regs) / cvt+ds_write-late (T14).

typedef __bf16 bf16;
typedef __attribute__((ext_vector_type(8))) __bf16 bf16x8;
typedef __attribute__((ext_vector_type(4))) float f32x4;

#define AS1 __attribute__((address_space(1)))
#define AS3 __attribute__((address_space(3)))

// ---------------------------------------------------------------------------
// fragment read: 8 contiguous bf16 (16B) = global k-chunk kc of LDS row `row`
// (XOR chunk swizzle: LDS slot c holds global chunk c ^ (row&7))
// ---------------------------------------------------------------------------
__device__ __forceinline__ bf16x8 fragld(const bf16* s, int row, int kc) {
  const int c = kc ^ (row & 7);
  return *(const bf16x8*)(s + row * 64 + c * 8);
}

// ---------------------------------------------------------------------------
// async DMA staging (512 threads): ROWSx64 bf16 tile, XOR-swizzled.
// per wave dest = uniform base + lane*16B (required by global_load_lds).
// ---------------------------------------------------------------------------
template <int ROWS>
__device__ __forceinline__ void stage_dma(const bf16* __restrict__ g, size_t row0,
                                          int ld, int kb, bf16* s, int t) {
#pragma unroll
  for (int i = 0; i < ROWS / 64; ++i) {
    const int r  = i * 64 + (t >> 3);
    const int c  = t & 7;
    const int cg = c ^ (r & 7);
    const bf16* gp = g + (row0 + (size_t)r) * (size_t)ld + (size_t)(kb + cg * 8);
    bf16* sp = s + i * 4096 + t * 8;
    __builtin_amdgcn_global_load_lds((const AS1 void*)gp, (AS3 void*)sp, 16, 0, 0);
  }
}

// split f32 staging: issue loads early (regs), cvt+ds_write after compute (T14)
__device__ __forceinline__ void stage_f32_load(const float* __restrict__ g, size_t row0,
                                               int ld, int kb, int t, float4* v) {
#pragma unroll
  for (int i = 0; i < 2; ++i) {
    const int r  = i * 64 + (t >> 3);
    const int c  = t & 7;
    const int cg = c ^ (r & 7);
    const float* p = g + (row0 + (size_t)r) * (size_t)ld + (size_t)(kb + cg * 8);
    v[2 * i]     = *(const float4*)(p);
    v[2 * i + 1] = *(const float4*)(p + 4);
  }
}

__device__ __forceinline__ void stage_f32_write(bf16* s, int t, const float4* v) {
#pragma unroll
  for (int i = 0; i < 2; ++i) {
    const int r = i * 64 + (t >> 3);
    const int c = t & 7;
    bf16x8 w;
    w[0] = (bf16)v[2 * i].x;     w[1] = (bf16)v[2 * i].y;
    w[2] = (bf16)v[2 * i].z;     w[3] = (bf16)v[2 * i].w;
    w[4] = (bf16)v[2 * i + 1].x; w[5] = (bf16)v[2 * i + 1].y;
    w[6] = (bf16)v[2 * i + 1].z; w[7] = (bf16)v[2 * i + 1].w;
    *(bf16x8*)(s + r * 64 + c * 8) = w;
  }
}

// ---------------------------------------------------------------------------
// 32x32 tiled transpose f32 -> bf16 (weights: <= 2MB each)
// ---------------------------------------------------------------------------
__global__ void transpose_cvt(const float* __restrict__ in, bf16* __restrict__ out,
                              int R, int C) {
  __shared__ float tile[32][33];
  const int bx = blockIdx.x * 32;  // col
  const int by = blockIdx.y * 32;  // row
  const int tx = threadIdx.x, ty = threadIdx.y;  // (32,8)
#pragma unroll
  for (int i = 0; i < 32; i += 8) tile[ty + i][tx] = in[(size_t)(by + ty + i) * C + bx + tx];
  __syncthreads();
#pragma unroll
  for (int i = 0; i < 32; i += 8) out[(size_t)(bx + ty + i) * R + by + tx] = (bf16)tile[tx][ty + i];
}

// ---------------------------------------------------------------------------
// GEMM1: emb = relu(bags[80000,1024](f32) @ W_enc + b_enc) -> bf16 [80000,512]
// Bt = W_enc^T bf16 [512,1024]. Block: m-tile 128 rows, loops nc in {0,1}
// (256 cols each), 16 K-steps per nc -> 32 pipelined steps total.
// 8 waves: wm in {0,1} (64-row half), wn in {0..3} (64-col strip), acc 4x4.
// 2-phase double-buffered LDS (2 x [sA 16KB | sB 32KB] = 96KB).
// ---------------------------------------------------------------------------
__global__ __launch_bounds__(512, 2) void gemm_enc(const float* __restrict__ A,
                                                   const bf16* __restrict__ Bt,
                                                   const float* __restrict__ bias,
                                                   bf16* __restrict__ Cout) {
  __shared__ bf16 smem[2 * 24576];  // [buf][sA 128x64 | sB 256x64]
  const int t = threadIdx.x;
  const int lane = t & 63, wave = t >> 6;
  const int wm = wave >> 2, wn = wave & 3;
  const size_t m0 = (size_t)blockIdx.x * 128;
  const int lm = lane & 15, lq = lane >> 4;

  f32x4 acc[4][4];
  float4 pref[4];
  int cur = 0;

  // prologue: stage step 0 (nc=0, kb=0) into buf0
  stage_dma<256>(Bt, 0, 1024, 0, smem + 8192, t);
  stage_f32_load(A, m0, 1024, 0, t, pref);
  stage_f32_write(smem, t, pref);

  for (int s = 0; s < 32; ++s) {
    if ((s & 15) == 0) {
#pragma unroll
      for (int i = 0; i < 4; ++i)
#pragma unroll
        for (int j = 0; j < 4; ++j) acc[i][j] = f32x4{0.f, 0.f, 0.f, 0.f};
    }
    __syncthreads();  // buf[cur] staged (vmcnt+lgkm drained), buf[cur^1] free
    const bf16* sA = smem + cur * 24576;
    const bf16* sB = sA + 8192;
    bf16* nb = smem + (cur ^ 1) * 24576;
    const bool pf = (s + 1 < 32);
    if (pf) {  // issue next step's staging BEFORE compute
      const int nc1 = (s + 1) >> 4, kb1 = ((s + 1) & 15) << 6;
      stage_dma<256>(Bt, (size_t)(nc1 * 256), 1024, kb1, nb + 8192, t);
      stage_f32_load(A, m0, 1024, kb1, t, pref);
    }
#pragma unroll
    for (int kk = 0; kk < 2; ++kk) {
      bf16x8 af[4];
#pragma unroll
      for (int mi = 0; mi < 4; ++mi) af[mi] = fragld(sA, wm * 64 + mi * 16 + lm, kk * 4 + lq);
#pragma unroll
      for (int ni = 0; ni < 4; ++ni) {
        const bf16x8 bfr = fragld(sB, wn * 64 + ni * 16 + lm, kk * 4 + lq);
#pragma unroll
        for (int mi = 0; mi < 4; ++mi)
          acc[mi][ni] = __builtin_amdgcn_mfma_f32_16x16x32_bf16(af[mi], bfr, acc[mi][ni], 0, 0, 0);
      }
    }
    if (pf) stage_f32_write(nb, t, pref);  // A cvt+write after MFMAs (latency hidden)
    cur ^= 1;
    if ((s & 15) == 15) {
      // epilogue for this nc: bias + relu, store bf16. D: col=lm, row=lq*4+r.
      const int n0 = (s >> 4) * 256;
#pragma unroll
      for (int ni = 0; ni < 4; ++ni) {
        const int n_g = n0 + wn * 64 + ni * 16 + lm;
        const float bz = bias[n_g];
#pragma unroll
        for (int mi = 0; mi < 4; ++mi) {
#pragma unroll
          for (int r = 0; r < 4; ++r) {
            const size_t m_g = m0 + (size_t)(wm * 64 + mi * 16 + lq * 4 + r);
            const float v = acc[mi][ni][r] + bz;
            Cout[m_g * 512 + n_g] = (bf16)fmaxf(v, 0.f);
          }
        }
      }
    }
  }
}

// ---------------------------------------------------------------------------
// GEMM2 (fused gate + attention logits), atomic-free:
//   hu = emb@W_u + b_u ; hv = emb@W_v + b_v ; g = sigmoid(hu)*tanh(hv)
//   logits[m,c] = sum_z g[m,z] * W_attn[c,z]
// Block owns m-tile of 128 rows; loops nc in {0..3} (128 z-cols each), 8
// K-steps per nc -> 32 pipelined steps. 8 waves: wm in {0,1} (64-row half),
// wn in {0..3} (32-col strip); wave tile 64x32 of BOTH U and V (acc 64 regs).
// Per-lane pc[mi][r][c] accumulates z-partials across all chunks; one shuffle
// tree + small LDS cross-wave reduce at the end; single coalesced store.
// ---------------------------------------------------------------------------
__global__ __launch_bounds__(512, 2) void gemm_gate(const bf16* __restrict__ A,
                                                    const bf16* __restrict__ But,
                                                    const bf16* __restrict__ Bvt,
                                                    const float* __restrict__ bu,
                                                    const float* __restrict__ bv,
                                                    const float* __restrict__ Wa,
                                                    float* __restrict__ logits) {
  __shared__ bf16 smem[2 * 24576];   // [buf][sA 128x64 | sU 128x64 | sV 128x64]
  __shared__ float red[8][64][4];    // cross-wave logits reduce (8KB)
  const int t = threadIdx.x;
  const int lane = t & 63, wave = t >> 6;
  const int wm = wave >> 2, wn = wave & 3;
  const size_t m0 = (size_t)blockIdx.x * 128;
  const int lm = lane & 15, lq = lane >> 4;

  f32x4 accU[4][2], accV[4][2];
  float pc[4][4][4];  // [mi][r][c] per-lane partial logits
#pragma unroll
  for (int mi = 0; mi < 4; ++mi)
#pragma unroll
    for (int r = 0; r < 4; ++r)
#pragma unroll
      for (int c = 0; c < 4; ++c) pc[mi][r][c] = 0.f;

  int cur = 0;
  // prologue: stage step 0 (nc=0, kb=0) into buf0
  stage_dma<128>(A,   m0, 512, 0, smem, t);
  stage_dma<128>(But, 0,  512, 0, smem + 8192, t);
  stage_dma<128>(Bvt, 0,  512, 0, smem + 16384, t);

  for (int s = 0; s < 32; ++s) {
    if ((s & 7) == 0) {
#pragma unroll
      for (int i = 0; i < 4; ++i)
#pragma unroll
        for (int j = 0; j < 2; ++j) {
          accU[i][j] = f32x4{0.f, 0.f, 0.f, 0.f};
          accV[i][j] = f32x4{0.f, 0.f, 0.f, 0.f};
        }
    }
    __syncthreads();
    const bf16* base = smem + cur * 24576;
    if (s + 1 < 32) {  // prefetch next step into the other buffer
      const int nc1 = (s + 1) >> 3, kb1 = ((s + 1) & 7) << 6;
      bf16* nb = smem + (cur ^ 1) * 24576;
      stage_dma<128>(A,   m0,                   512, kb1, nb, t);
      stage_dma<128>(But, (size_t)(nc1 * 128),  512, kb1, nb + 8192, t);
      stage_dma<128>(Bvt, (size_t)(nc1 * 128),  512, kb1, nb + 16384, t);
    }
#pragma unroll
    for (int kk = 0; kk < 2; ++kk) {
      bf16x8 af[4];
#pragma unroll
      for (int mi = 0; mi < 4; ++mi) af[mi] = fragld(base, wm * 64 + mi * 16 + lm, kk * 4 + lq);
#pragma unroll
      for (int ni = 0; ni < 2; ++ni) {
        const int row = wn * 32 + ni * 16 + lm;
        const bf16x8 bu8 = fragld(base + 8192,  row, kk * 4 + lq);
        const bf16x8 bv8 = fragld(base + 16384, row, kk * 4 + lq);
#pragma unroll
        for (int mi = 0; mi < 4; ++mi)
          accU[mi][ni] = __builtin_amdgcn_mfma_f32_16x16x32_bf16(af[mi], bu8, accU[mi][ni], 0, 0, 0);
#pragma unroll
        for (int mi = 0; mi < 4; ++mi)
          accV[mi][ni] = __builtin_amdgcn_mfma_f32_16x16x32_bf16(af[mi], bv8, accV[mi][ni], 0, 0, 0);
      }
    }
    cur ^= 1;
    if ((s & 7) == 7) {
      // nonlinearity + W_attn contraction for this z-chunk, accumulate into pc
      const int nc = s >> 3;
#pragma unroll
      for (int ni = 0; ni < 2; ++ni) {
        const int n_g = nc * 128 + wn * 32 + ni * 16 + lm;
        const float bzu = bu[n_g], bzv = bv[n_g];
        float wac[4];
#pragma unroll
        for (int c = 0; c < 4; ++c) wac[c] = Wa[c * 512 + n_g];
#pragma unroll
        for (int mi = 0; mi < 4; ++mi) {
#pragma unroll
          for (int r = 0; r < 4; ++r) {
            const float hu = accU[mi][ni][r] + bzu;
            const float hv = accV[mi][ni][r] + bzv;
            const float sg = __builtin_amdgcn_rcpf(1.f + __expf(-hu));
            const float th = 1.f - 2.f * __builtin_amdgcn_rcpf(1.f + __expf(2.f * hv));
            const float g = sg * th;
#pragma unroll
            for (int c = 0; c < 4; ++c) pc[mi][r][c] += g * wac[c];
          }
        }
      }
    }
  }

  // reduce pc over the 16 lanes (lm bits) sharing each output row
#pragma unroll
  for (int mi = 0; mi < 4; ++mi)
#pragma unroll
    for (int r = 0; r < 4; ++r)
#pragma unroll
      for (int c = 0; c < 4; ++c) {
#pragma unroll
        for (int o = 8; o >= 1; o >>= 1) pc[mi][r][c] += __shfl_xor(pc[mi][r][c], o);
      }
  if (lm == 0) {
#pragma unroll
    for (int mi = 0; mi < 4; ++mi)
#pragma unroll
      for (int r = 0; r < 4; ++r)
#pragma unroll
        for (int c = 0; c < 4; ++c) red[wave][mi * 16 + lq * 4 + r][c] = pc[mi][r][c];
  }
  __syncthreads();
  // cross-wn sum and single store: thread t -> (row, c)
  {
    const int row = t >> 2, c = t & 3;
    const int wmr = row >> 6, loc = row & 63;
    const float v = red[wmr * 4 + 0][loc][c] + red[wmr * 4 + 1][loc][c] +
                    red[wmr * 4 + 2][loc][c] + red[wmr * 4 + 3][loc][c];
    logits[(m0 + (size_t)row) * 4 + c] = v;
  }
}

// ---------------------------------------------------------------------------
// softmax over N per (b,c); rewrites logits buffer in place with attn weights.
// b_attn omitted: constant shift per (b,c) cancels in softmax.
// ---------------------------------------------------------------------------
__global__ void softmax_attn(float* __restrict__ logits) {
  const int b = blockIdx.x >> 2, c = blockIdx.x & 3;
  float* base = logits + (size_t)b * 10000 * 4 + c;
  const int t = threadIdx.x;
  const int lane = t & 63, w = t >> 6;
  __shared__ float red[8];

  float m = -3.0e38f;
  for (int n = t; n < 10000; n += 256) m = fmaxf(m, base[(size_t)n * 4]);
#pragma unroll
  for (int o = 32; o >= 1; o >>= 1) m = fmaxf(m, __shfl_xor(m, o));
  if (lane == 0) red[w] = m;
  __syncthreads();
  m = fmaxf(fmaxf(red[0], red[1]), fmaxf(red[2], red[3]));

  float s = 0.f;
  for (int n = t; n < 10000; n += 256) s += __expf(base[(size_t)n * 4] - m);
#pragma unroll
  for (int o = 32; o >= 1; o >>= 1) s += __shfl_xor(s, o);
  if (lane == 0) red[4 + w] = s;
  __syncthreads();
  s = red[4] + red[5] + red[6] + red[7];

  const float rs = 1.f / s;
  for (int n = t; n < 10000; n += 256) base[(size_t)n * 4] = __expf(base[(size_t)n * 4] - m) * rs;
}

// ---------------------------------------------------------------------------
// scores[b,c] = sum_n attn[b,n,c] * (emb[b,n,:] . W_cls[c,:])
// block = (b, chunk of 250 rows); 4 waves, wave-per-row round robin.
// ---------------------------------------------------------------------------
__global__ __launch_bounds__(256) void scores_partial(const bf16* __restrict__ emb,
                                                      const float* __restrict__ attn,
                                                      const float* __restrict__ Wcls,
                                                      float* __restrict__ sacc) {
  const int b = blockIdx.x;
  const int chunk = blockIdx.y;
  const int t = threadIdx.x;
  const int wave = t >> 6, lane = t & 63;

  float wcl[4][8];
#pragma unroll
  for (int c = 0; c < 4; ++c) {
    const float4 wlo = *(const float4*)(Wcls + c * 512 + lane * 8);
    const float4 whi = *(const float4*)(Wcls + c * 512 + lane * 8 + 4);
    wcl[c][0] = wlo.x; wcl[c][1] = wlo.y; wcl[c][2] = wlo.z; wcl[c][3] = wlo.w;
    wcl[c][4] = whi.x; wcl[c][5] = whi.y; wcl[c][6] = whi.z; wcl[c][7] = whi.w;
  }

  float acc[4] = {0.f, 0.f, 0.f, 0.f};
  const int nbeg = chunk * 250, nend = nbeg + 250;
  for (int n = nbeg + wave; n < nend; n += 4) {
    const size_t row = (size_t)b * 10000 + n;
    const bf16x8 e8 = *(const bf16x8*)(emb + row * 512 + lane * 8);
    float d[4] = {0.f, 0.f, 0.f, 0.f};
#pragma unroll
    for (int j = 0; j < 8; ++j) {
      const float e = (float)e8[j];
#pragma unroll
      for (int c = 0; c < 4; ++c) d[c] += e * wcl[c][j];
    }
#pragma unroll
    for (int o = 32; o >= 1; o >>= 1) {
#pragma unroll
      for (int c = 0; c < 4; ++c) d[c] += __shfl_xor(d[c], o);
    }
    const float4 wv = *(const float4*)(attn + row * 4);
    acc[0] += wv.x * d[0];
    acc[1] += wv.y * d[1];
    acc[2] += wv.z * d[2];
    acc[3] += wv.w * d[3];
  }
  if (lane == 0) {
#pragma unroll
    for (int c = 0; c < 4; ++c) atomicAdd(&sacc[b * 4 + c], acc[c]);
  }
}

__global__ void finalize(const float* __restrict__ sacc, const float* __restrict__ b_cls,
                         float* __restrict__ out) {
  const int i = threadIdx.x;
  if (i < 32) out[i] = sacc[i] + b_cls[i & 3];
}

// ---------------------------------------------------------------------------
extern "C" void kernel_launch(void* const* d_in, const int* in_sizes, int n_in,
                              void* d_out, int out_size, void* d_ws, size_t ws_size,
                              hipStream_t stream) {
  (void)in_sizes; (void)n_in; (void)out_size; (void)ws_size;
  const float* bags   = (const float*)d_in[0];
  const float* W_enc  = (const float*)d_in[1];
  const float* b_enc  = (const float*)d_in[2];
  const float* W_u    = (const float*)d_in[3];
  const float* b_u    = (const float*)d_in[4];
  const float* W_v    = (const float*)d_in[5];
  const float* b_v    = (const float*)d_in[6];
  const float* W_attn = (const float*)d_in[7];
  // d_in[8] = b_attn: unused (cancels in softmax over instances)
  const float* W_cls  = (const float*)d_in[9];
  const float* b_cls  = (const float*)d_in[10];
  float* out = (float*)d_out;

  char* ws = (char*)d_ws;
  bf16*  emb    = (bf16*)(ws);                       // 80000*512*2  = 81,920,000 B
  float* logits = (float*)(ws + 81920000);           // 80000*4*4   =  1,280,000 B
  bf16*  WencT  = (bf16*)(ws + 83200000);            // 512*1024*2  =  1,048,576 B
  bf16*  WuT    = (bf16*)(ws + 84248576);            // 512*512*2   =    524,288 B
  bf16*  WvT    = (bf16*)(ws + 84772864);            // 512*512*2   =    524,288 B
  float* sacc   = (float*)(ws + 85297152);           // 32*4        =        128 B

  hipMemsetAsync(sacc, 0, 32 * sizeof(float), stream);

  transpose_cvt<<<dim3(16, 32), dim3(32, 8), 0, stream>>>(W_enc, WencT, 1024, 512);
  transpose_cvt<<<dim3(16, 16), dim3(32, 8), 0, stream>>>(W_u, WuT, 512, 512);
  transpose_cvt<<<dim3(16, 16), dim3(32, 8), 0, stream>>>(W_v, WvT, 512, 512);

  gemm_enc<<<625, 512, 0, stream>>>(bags, WencT, b_enc, emb);
  gemm_gate<<<625, 512, 0, stream>>>(emb, WuT, WvT, b_u, b_v, W_attn, logits);
  softmax_attn<<<32, 256, 0, stream>>>(logits);
  scores_partial<<<dim3(8, 40), 256, 0, stream>>>(emb, logits, W_cls, sacc);
  finalize<<<1, 64, 0, stream>>>(sacc, b_cls, out);
}

// Round 2
// 736.848 us; speedup vs baseline: 1.1515x; 1.1508x over previous
//
#include <hip/hip_runtime.h>
#include <hip/hip_bf16.h>
#include <cstdint>

// CLAM-MIL forward. Inputs/outputs FLOAT32; internal compute bf16 MFMA + fp32 accum.
// B=8, N=10000 (M=80000 rows), F=1024, Z=512, C=4.
//
// Round 7: counted-vmcnt pipeline (T4). Round-6 post-mortem: __syncthreads drains
// vmcnt(0) -> both GEMMs latency-bound at ~5800 cyc/step (MfmaUtil 14%). Now:
// raw s_barrier + asm s_waitcnt vmcnt(N), 3 LDS buffers, stage step s+2 while
// computing step s (2 iterations of latency budget, never drain to 0 mid-loop).
//  - enc: f32 A-loads via inline-asm global_load_dwordx4 (keeps compiler from
//    emitting vmcnt(0) before the cvt); C-store only at kernel end (stores must
//    not enter the counted vmcnt stream); grid 1250 + bijective XCD swizzle so
//    the 2 blocks sharing an A-tile sit on the same XCD L2.
//  - gate: epilogue consts (b_u/b_v/W_attn) preloaded to LDS (no mid-loop global
//    loads in the vmcnt stream); atomic-free logits, now in [c][80000] layout.
//  - softmax: contiguous float4 passes on the new layout.

typedef __bf16 bf16;
typedef __attribute__((ext_vector_type(8))) __bf16 bf16x8;
typedef __attribute__((ext_vector_type(4))) float f32x4;

#define AS1 __attribute__((address_space(1)))
#define AS3 __attribute__((address_space(3)))

#define WAITVM(N) asm volatile("s_waitcnt vmcnt(" #N ")" ::: "memory")
#define WAITLGKM0 asm volatile("s_waitcnt lgkmcnt(0)" ::: "memory")

// ---------------------------------------------------------------------------
// fragment read: 8 contiguous bf16 (16B) = global k-chunk kc of LDS row `row`
// (XOR chunk swizzle: LDS slot c holds global chunk c ^ (row&7))
// ---------------------------------------------------------------------------
__device__ __forceinline__ bf16x8 fragld(const bf16* s, int row, int kc) {
  const int c = kc ^ (row & 7);
  return *(const bf16x8*)(s + row * 64 + c * 8);
}

// ---------------------------------------------------------------------------
// async DMA staging (512 threads): ROWSx64 bf16 tile, XOR-swizzled.
// per wave dest = uniform base + lane*16B (required by global_load_lds).
// ---------------------------------------------------------------------------
template <int ROWS>
__device__ __forceinline__ void stage_dma(const bf16* __restrict__ g, size_t row0,
                                          int ld, int kb, bf16* s, int t) {
#pragma unroll
  for (int i = 0; i < ROWS / 64; ++i) {
    const int r  = i * 64 + (t >> 3);
    const int c  = t & 7;
    const int cg = c ^ (r & 7);
    const bf16* gp = g + (row0 + (size_t)r) * (size_t)ld + (size_t)(kb + cg * 8);
    bf16* sp = s + i * 4096 + t * 8;
    __builtin_amdgcn_global_load_lds((const AS1 void*)gp, (AS3 void*)sp, 16, 0, 0);
  }
}

// inline-asm f32x4 load: invisible to the compiler's waitcnt pass, so our
// counted WAITVM covers it (compiler would otherwise insert vmcnt(0)).
__device__ __forceinline__ float4 gload4(const float* p) {
  float4 r;
  asm volatile("global_load_dwordx4 %0, %1, off" : "=v"(r) : "v"(p) : "memory");
  return r;
}

// ---------------------------------------------------------------------------
// 32x32 tiled transpose f32 -> bf16 (weights: <= 2MB each)
// ---------------------------------------------------------------------------
__global__ void transpose_cvt(const float* __restrict__ in, bf16* __restrict__ out,
                              int R, int C) {
  __shared__ float tile[32][33];
  const int bx = blockIdx.x * 32;  // col
  const int by = blockIdx.y * 32;  // row
  const int tx = threadIdx.x, ty = threadIdx.y;  // (32,8)
#pragma unroll
  for (int i = 0; i < 32; i += 8) tile[ty + i][tx] = in[(size_t)(by + ty + i) * C + bx + tx];
  __syncthreads();
#pragma unroll
  for (int i = 0; i < 32; i += 8) out[(size_t)(bx + ty + i) * R + by + tx] = (bf16)tile[tx][ty + i];
}

// ---------------------------------------------------------------------------
// GEMM1: emb = relu(bags[80000,1024](f32) @ W_enc + b_enc) -> bf16 [80000,512]
// Bt = W_enc^T bf16 [512,1024]. Tile 128x256, BK=64, 16 K-steps, 512 threads
// (8 waves: wm row-half, wn 64-col strip; acc 4x4). 3-buffer counted-vmcnt
// pipeline: per iter issue A(s+3) f32->regs (asm), B(s+2) via global_load_lds,
// cvt+ds_write A(s+1); steady wait = vmcnt(8) (A(s+1)+B(s) done, 8 newer in
// flight). Fully unrolled so pref-slot indices are static (rule #20).
// ---------------------------------------------------------------------------
__global__ __launch_bounds__(512, 2) void gemm_enc(const float* __restrict__ A,
                                                   const bf16* __restrict__ Bt,
                                                   const float* __restrict__ bias,
                                                   bf16* __restrict__ Cout) {
  __shared__ bf16 smem[3 * 24576];  // 3 bufs x [A 128x64 | B 256x64] = 144 KB
  const int t = threadIdx.x;
  const int lane = t & 63, wave = t >> 6;
  const int wm = wave >> 2, wn = wave & 3;
  // bijective XCD swizzle (nwg=1250, q=156, r=2): blocks (2k,2k+1) -> same XCD,
  // so the shared 512KB A-tile's 2nd read is an L2 hit.
  const int bid = blockIdx.x;
  const int xcd = bid & 7, idx = bid >> 3;
  const int wg  = (xcd < 2 ? xcd * 157 : 314 + (xcd - 2) * 156) + idx;
  const size_t m0 = (size_t)(wg >> 1) * 128;
  const int n0 = (wg & 1) * 256;
  const int lm = lane & 15, lq = lane >> 4;

  // A f32 address bases: row r = i*64 + (t>>3), chunk cg = (t&7) ^ (r&7)
  const int ar0 = t >> 3, ac = t & 7;
  const float* aB0 = A + (m0 + (size_t)ar0) * 1024 + (size_t)((ac ^ (ar0 & 7)) * 8);
  const float* aB1 = aB0 + (size_t)64 * 1024;  // (64+r)&7 == r&7

  f32x4 acc[4][4];
#pragma unroll
  for (int i = 0; i < 4; ++i)
#pragma unroll
    for (int j = 0; j < 4; ++j) acc[i][j] = f32x4{0.f, 0.f, 0.f, 0.f};

  float4 pv[3][4];

#define LDA(kb, slot)                              \
  do {                                             \
    pv[slot][0] = gload4(aB0 + (kb));              \
    pv[slot][1] = gload4(aB0 + (kb) + 4);          \
    pv[slot][2] = gload4(aB1 + (kb));              \
    pv[slot][3] = gload4(aB1 + (kb) + 4);          \
  } while (0)

#define CVTW(bufA, slot)                                              \
  do {                                                                \
    bf16x8 w0, w1;                                                    \
    w0[0] = (bf16)pv[slot][0].x; w0[1] = (bf16)pv[slot][0].y;         \
    w0[2] = (bf16)pv[slot][0].z; w0[3] = (bf16)pv[slot][0].w;         \
    w0[4] = (bf16)pv[slot][1].x; w0[5] = (bf16)pv[slot][1].y;         \
    w0[6] = (bf16)pv[slot][1].z; w0[7] = (bf16)pv[slot][1].w;         \
    w1[0] = (bf16)pv[slot][2].x; w1[1] = (bf16)pv[slot][2].y;         \
    w1[2] = (bf16)pv[slot][2].z; w1[3] = (bf16)pv[slot][2].w;         \
    w1[4] = (bf16)pv[slot][3].x; w1[5] = (bf16)pv[slot][3].y;         \
    w1[6] = (bf16)pv[slot][3].z; w1[7] = (bf16)pv[slot][3].w;         \
    *(bf16x8*)((bufA) + t * 8) = w0;                                  \
    *(bf16x8*)((bufA) + 4096 + t * 8) = w1;                           \
  } while (0)

  // prologue: A(0),B(0),A(1),B(1),A(2) issued; cvt A(0) -> buf0
  LDA(0, 0);
  stage_dma<256>(Bt, (size_t)n0, 1024, 0, smem + 8192, t);
  LDA(64, 1);
  stage_dma<256>(Bt, (size_t)n0, 1024, 64, smem + 24576 + 8192, t);
  LDA(128, 2);
  WAITVM(12);  // A(0) done
  CVTW(smem, 0);

#pragma unroll
  for (int s = 0; s < 16; ++s) {
    if (s <= 13) { WAITVM(8); }       // A(s+1), B(s) done; A(s+2),B(s+1) in flight
    else if (s == 14) { WAITVM(4); }  // tail: only B(15) may remain
    else { WAITVM(0); }
    WAITLGKM0;                        // publish my ds_writes before barrier
    __builtin_amdgcn_s_barrier();
    __builtin_amdgcn_sched_barrier(0);
    bf16* bufc = smem + (s % 3) * 24576;
    if (s < 15) CVTW(smem + ((s + 1) % 3) * 24576, (s + 1) % 3);
    if (s < 13) LDA((s + 3) * 64, (s + 3) % 3);
    if (s < 14) stage_dma<256>(Bt, (size_t)n0, 1024, (s + 2) * 64,
                               smem + ((s + 2) % 3) * 24576 + 8192, t);
    const bf16* sA = bufc;
    const bf16* sB = bufc + 8192;
#pragma unroll
    for (int kk = 0; kk < 2; ++kk) {
      bf16x8 af[4];
#pragma unroll
      for (int mi = 0; mi < 4; ++mi) af[mi] = fragld(sA, wm * 64 + mi * 16 + lm, kk * 4 + lq);
#pragma unroll
      for (int ni = 0; ni < 4; ++ni) {
        const bf16x8 bfr = fragld(sB, wn * 64 + ni * 16 + lm, kk * 4 + lq);
#pragma unroll
        for (int mi = 0; mi < 4; ++mi)
          acc[mi][ni] = __builtin_amdgcn_mfma_f32_16x16x32_bf16(af[mi], bfr, acc[mi][ni], 0, 0, 0);
      }
    }
  }
#undef LDA
#undef CVTW

  // epilogue: bias + relu, store bf16. D layout: col=lane&15, row=lq*4+reg.
#pragma unroll
  for (int ni = 0; ni < 4; ++ni) {
    const int n_g = n0 + wn * 64 + ni * 16 + lm;
    const float bz = bias[n_g];
#pragma unroll
    for (int mi = 0; mi < 4; ++mi) {
#pragma unroll
      for (int r = 0; r < 4; ++r) {
        const size_t m_g = m0 + (size_t)(wm * 64 + mi * 16 + lq * 4 + r);
        const float v = acc[mi][ni][r] + bz;
        Cout[m_g * 512 + n_g] = (bf16)fmaxf(v, 0.f);
      }
    }
  }
}

// ---------------------------------------------------------------------------
// GEMM2 (fused gate + attention logits), atomic-free, counted-vmcnt:
//   hu = emb@W_u + b_u ; hv = emb@W_v + b_v ; g = sigmoid(hu)*tanh(hv)
//   logitsT[c][m] = sum_z g[m,z] * W_attn[c,z]
// Block owns 128 rows; 4 z-chunks x 8 K-steps = 32 steps, 3-buffer rotation,
// stage(s+2) per iter, steady wait vmcnt(6). Epilogue consts live in LDS
// (preloaded once) so no global loads enter the counted vmem stream.
// ---------------------------------------------------------------------------
__global__ __launch_bounds__(512, 2) void gemm_gate(const bf16* __restrict__ A,
                                                    const bf16* __restrict__ But,
                                                    const bf16* __restrict__ Bvt,
                                                    const float* __restrict__ bu,
                                                    const float* __restrict__ bv,
                                                    const float* __restrict__ Wa,
                                                    float* __restrict__ logitsT) {
  // 3 x [sA 128x64 | sU 128x64 | sV 128x64] (144KB) + consts 12KB = 156KB
  __shared__ bf16 smem[3 * 24576 + 6144];
  float* sBu = (float*)(smem + 73728);
  float* sBv = sBu + 512;
  float* sWa = sBv + 512;  // 2048 floats, layout [c][z]
  const int t = threadIdx.x;
  const int lane = t & 63, wave = t >> 6;
  const int wm = wave >> 2, wn = wave & 3;
  const size_t m0 = (size_t)blockIdx.x * 128;
  const int lm = lane & 15, lq = lane >> 4;

  // preload epilogue consts into LDS (before any DMA issues)
  sBu[t] = bu[t];
  sBv[t] = bv[t];
  ((float4*)sWa)[t] = ((const float4*)Wa)[t];

  f32x4 accU[4][2], accV[4][2];
  float pc[4][4][4];  // [mi][r][c] per-lane partial logits
#pragma unroll
  for (int mi = 0; mi < 4; ++mi)
#pragma unroll
    for (int r = 0; r < 4; ++r)
#pragma unroll
      for (int c = 0; c < 4; ++c) pc[mi][r][c] = 0.f;

  // prologue: stage steps 0 and 1
  stage_dma<128>(A,   m0, 512, 0, smem, t);
  stage_dma<128>(But, 0,  512, 0, smem + 8192, t);
  stage_dma<128>(Bvt, 0,  512, 0, smem + 16384, t);
  stage_dma<128>(A,   m0, 512, 64, smem + 24576, t);
  stage_dma<128>(But, 0,  512, 64, smem + 24576 + 8192, t);
  stage_dma<128>(Bvt, 0,  512, 64, smem + 24576 + 16384, t);

  for (int s = 0; s < 32; ++s) {
    if ((s & 7) == 0) {
#pragma unroll
      for (int i = 0; i < 4; ++i)
#pragma unroll
        for (int j = 0; j < 2; ++j) {
          accU[i][j] = f32x4{0.f, 0.f, 0.f, 0.f};
          accV[i][j] = f32x4{0.f, 0.f, 0.f, 0.f};
        }
    }
    if (s == 31) { WAITVM(0); } else { WAITVM(6); }  // stage(s) done, stage(s+1) in flight
    WAITLGKM0;  // publish const ds_writes (iter 0); later iters free
    __builtin_amdgcn_s_barrier();
    __builtin_amdgcn_sched_barrier(0);
    const bf16* base = smem + (s % 3) * 24576;
    if (s < 30) {  // stage step s+2 into the buffer freed by iter s-1
      const int st = s + 2, nc1 = st >> 3, kb1 = (st & 7) << 6;
      bf16* nb = smem + (st % 3) * 24576;
      stage_dma<128>(A,   m0,                  512, kb1, nb, t);
      stage_dma<128>(But, (size_t)(nc1 * 128), 512, kb1, nb + 8192, t);
      stage_dma<128>(Bvt, (size_t)(nc1 * 128), 512, kb1, nb + 16384, t);
    }
#pragma unroll
    for (int kk = 0; kk < 2; ++kk) {
      bf16x8 af[4];
#pragma unroll
      for (int mi = 0; mi < 4; ++mi) af[mi] = fragld(base, wm * 64 + mi * 16 + lm, kk * 4 + lq);
#pragma unroll
      for (int ni = 0; ni < 2; ++ni) {
        const int row = wn * 32 + ni * 16 + lm;
        const bf16x8 bu8 = fragld(base + 8192,  row, kk * 4 + lq);
        const bf16x8 bv8 = fragld(base + 16384, row, kk * 4 + lq);
#pragma unroll
        for (int mi = 0; mi < 4; ++mi)
          accU[mi][ni] = __builtin_amdgcn_mfma_f32_16x16x32_bf16(af[mi], bu8, accU[mi][ni], 0, 0, 0);
#pragma unroll
        for (int mi = 0; mi < 4; ++mi)
          accV[mi][ni] = __builtin_amdgcn_mfma_f32_16x16x32_bf16(af[mi], bv8, accV[mi][ni], 0, 0, 0);
      }
    }
    if ((s & 7) == 7) {
      // nonlinearity + W_attn contraction for this z-chunk (consts from LDS)
      const int nc = s >> 3;
#pragma unroll
      for (int ni = 0; ni < 2; ++ni) {
        const int n_g = nc * 128 + wn * 32 + ni * 16 + lm;
        const float bzu = sBu[n_g], bzv = sBv[n_g];
        float wac[4];
#pragma unroll
        for (int c = 0; c < 4; ++c) wac[c] = sWa[c * 512 + n_g];
#pragma unroll
        for (int mi = 0; mi < 4; ++mi) {
#pragma unroll
          for (int r = 0; r < 4; ++r) {
            const float hu = accU[mi][ni][r] + bzu;
            const float hv = accV[mi][ni][r] + bzv;
            const float sg = __builtin_amdgcn_rcpf(1.f + __expf(-hu));
            const float th = 1.f - 2.f * __builtin_amdgcn_rcpf(1.f + __expf(2.f * hv));
            const float g = sg * th;
#pragma unroll
            for (int c = 0; c < 4; ++c) pc[mi][r][c] += g * wac[c];
          }
        }
      }
    }
  }

  // reduce pc over the 16 lanes (lm bits) sharing each output row
#pragma unroll
  for (int mi = 0; mi < 4; ++mi)
#pragma unroll
    for (int r = 0; r < 4; ++r)
#pragma unroll
      for (int c = 0; c < 4; ++c) {
#pragma unroll
        for (int o = 8; o >= 1; o >>= 1) pc[mi][r][c] += __shfl_xor(pc[mi][r][c], o);
      }
  // red aliases buf0 space (safe: buf0 last read at s=30, barrier-protected)
  float (*red)[64][4] = (float (*)[64][4])smem;
  if (lm == 0) {
#pragma unroll
    for (int mi = 0; mi < 4; ++mi)
#pragma unroll
      for (int r = 0; r < 4; ++r)
#pragma unroll
        for (int c = 0; c < 4; ++c) red[wave][mi * 16 + lq * 4 + r][c] = pc[mi][r][c];
  }
  __syncthreads();
  // cross-wn sum + coalesced store: threads 0..127 -> c=0 rows m0..m0+127, etc.
  {
    const int row = t & 127, c = t >> 7;
    const int wmr = row >> 6, loc = row & 63;
    const float v = red[wmr * 4 + 0][loc][c] + red[wmr * 4 + 1][loc][c] +
                    red[wmr * 4 + 2][loc][c] + red[wmr * 4 + 3][loc][c];
    logitsT[(size_t)c * 80000 + m0 + row] = v;
  }
}

// ---------------------------------------------------------------------------
// softmax over N per (b,c) on logitsT [c][b][n] layout: 32 contiguous rows of
// 10000 floats. float4 passes, in-place rewrite with attn weights.
// b_attn omitted: constant shift per (b,c) cancels in softmax.
// ---------------------------------------------------------------------------
__global__ void softmax_attn(float* __restrict__ logits) {
  float* base = logits + (size_t)blockIdx.x * 10000;
  float4* b4 = (float4*)base;
  const int t = threadIdx.x;
  const int lane = t & 63, w = t >> 6;
  __shared__ float red[8];

  float m = -3.0e38f;
  for (int i = t; i < 2500; i += 256) {
    const float4 v = b4[i];
    m = fmaxf(m, fmaxf(fmaxf(v.x, v.y), fmaxf(v.z, v.w)));
  }
#pragma unroll
  for (int o = 32; o >= 1; o >>= 1) m = fmaxf(m, __shfl_xor(m, o));
  if (lane == 0) red[w] = m;
  __syncthreads();
  m = fmaxf(fmaxf(red[0], red[1]), fmaxf(red[2], red[3]));

  float s = 0.f;
  for (int i = t; i < 2500; i += 256) {
    const float4 v = b4[i];
    s += __expf(v.x - m) + __expf(v.y - m) + __expf(v.z - m) + __expf(v.w - m);
  }
#pragma unroll
  for (int o = 32; o >= 1; o >>= 1) s += __shfl_xor(s, o);
  if (lane == 0) red[4 + w] = s;
  __syncthreads();
  s = red[4] + red[5] + red[6] + red[7];

  const float rs = 1.f / s;
  for (int i = t; i < 2500; i += 256) {
    float4 v = b4[i];
    v.x = __expf(v.x - m) * rs;
    v.y = __expf(v.y - m) * rs;
    v.z = __expf(v.z - m) * rs;
    v.w = __expf(v.w - m) * rs;
    b4[i] = v;
  }
}

// ---------------------------------------------------------------------------
// scores[b,c] = sum_n attn[b,n,c] * (emb[b,n,:] . W_cls[c,:])
// attn now in [c][80000] layout. block = (b, chunk of 250 rows).
// ---------------------------------------------------------------------------
__global__ __launch_bounds__(256) void scores_partial(const bf16* __restrict__ emb,
                                                      const float* __restrict__ attn,
                                                      const float* __restrict__ Wcls,
                                                      float* __restrict__ sacc) {
  const int b = blockIdx.x;
  const int chunk = blockIdx.y;
  const int t = threadIdx.x;
  const int wave = t >> 6, lane = t & 63;

  float wcl[4][8];
#pragma unroll
  for (int c = 0; c < 4; ++c) {
    const float4 wlo = *(const float4*)(Wcls + c * 512 + lane * 8);
    const float4 whi = *(const float4*)(Wcls + c * 512 + lane * 8 + 4);
    wcl[c][0] = wlo.x; wcl[c][1] = wlo.y; wcl[c][2] = wlo.z; wcl[c][3] = wlo.w;
    wcl[c][4] = whi.x; wcl[c][5] = whi.y; wcl[c][6] = whi.z; wcl[c][7] = whi.w;
  }

  float acc[4] = {0.f, 0.f, 0.f, 0.f};
  const int nbeg = chunk * 250, nend = nbeg + 250;
  for (int n = nbeg + wave; n < nend; n += 4) {
    const size_t row = (size_t)b * 10000 + n;
    const bf16x8 e8 = *(const bf16x8*)(emb + row * 512 + lane * 8);
    float d[4] = {0.f, 0.f, 0.f, 0.f};
#pragma unroll
    for (int j = 0; j < 8; ++j) {
      const float e = (float)e8[j];
#pragma unroll
      for (int c = 0; c < 4; ++c) d[c] += e * wcl[c][j];
    }
#pragma unroll
    for (int o = 32; o >= 1; o >>= 1) {
#pragma unroll
      for (int c = 0; c < 4; ++c) d[c] += __shfl_xor(d[c], o);
    }
#pragma unroll
    for (int c = 0; c < 4; ++c) acc[c] += attn[(size_t)c * 80000 + row] * d[c];
  }
  if (lane == 0) {
#pragma unroll
    for (int c = 0; c < 4; ++c) atomicAdd(&sacc[b * 4 + c], acc[c]);
  }
}

__global__ void finalize(const float* __restrict__ sacc, const float* __restrict__ b_cls,
                         float* __restrict__ out) {
  const int i = threadIdx.x;
  if (i < 32) out[i] = sacc[i] + b_cls[i & 3];
}

// ---------------------------------------------------------------------------
extern "C" void kernel_launch(void* const* d_in, const int* in_sizes, int n_in,
                              void* d_out, int out_size, void* d_ws, size_t ws_size,
                              hipStream_t stream) {
  (void)in_sizes; (void)n_in; (void)out_size; (void)ws_size;
  const float* bags   = (const float*)d_in[0];
  const float* W_enc  = (const float*)d_in[1];
  const float* b_enc  = (const float*)d_in[2];
  const float* W_u    = (const float*)d_in[3];
  const float* b_u    = (const float*)d_in[4];
  const float* W_v    = (const float*)d_in[5];
  const float* b_v    = (const float*)d_in[6];
  const float* W_attn = (const float*)d_in[7];
  // d_in[8] = b_attn: unused (cancels in softmax over instances)
  const float* W_cls  = (const float*)d_in[9];
  const float* b_cls  = (const float*)d_in[10];
  float* out = (float*)d_out;

  char* ws = (char*)d_ws;
  bf16*  emb     = (bf16*)(ws);                      // 80000*512*2  = 81,920,000 B
  float* logitsT = (float*)(ws + 81920000);          // 4*80000*4   =  1,280,000 B
  bf16*  WencT   = (bf16*)(ws + 83200000);           // 512*1024*2  =  1,048,576 B
  bf16*  WuT     = (bf16*)(ws + 84248576);           // 512*512*2   =    524,288 B
  bf16*  WvT     = (bf16*)(ws + 84772864);           // 512*512*2   =    524,288 B
  float* sacc    = (float*)(ws + 85297152);          // 32*4        =        128 B

  hipMemsetAsync(sacc, 0, 32 * sizeof(float), stream);

  transpose_cvt<<<dim3(16, 32), dim3(32, 8), 0, stream>>>(W_enc, WencT, 1024, 512);
  transpose_cvt<<<dim3(16, 16), dim3(32, 8), 0, stream>>>(W_u, WuT, 512, 512);
  transpose_cvt<<<dim3(16, 16), dim3(32, 8), 0, stream>>>(W_v, WvT, 512, 512);

  gemm_enc<<<1250, 512, 0, stream>>>(bags, WencT, b_enc, emb);
  gemm_gate<<<625, 512, 0, stream>>>(emb, WuT, WvT, b_u, b_v, W_attn, logitsT);
  softmax_attn<<<32, 256, 0, stream>>>(logitsT);
  scores_partial<<<dim3(8, 40), 256, 0, stream>>>(emb, logitsT, W_cls, sacc);
  finalize<<<1, 64, 0, stream>>>(sacc, b_cls, out);
}

// Round 3
// 656.057 us; speedup vs baseline: 1.2933x; 1.1231x over previous
//
#include <hip/hip_runtime.h>
#include <hip/hip_bf16.h>
#include <cstdint>

// CLAM-MIL forward. Inputs/outputs FLOAT32; internal compute bf16 MFMA + fp32 accum.
// B=8, N=10000 (M=80000 rows), F=1024, Z=512, C=4.
//
// Round 8: small-kernel cleanup + calibration round.
//  - scores_partial: shuffle-free main loop (reps-accumulation by linearity:
//    acc[c][z-slice] += attn[c,n]*emb[n,z-slice]; dot with W_cls once at end).
//    Was: 24 shfl+24 add per row per class-group -> serialized. Now 32 FMA/row.
//    Grid (8,64) = 512 blocks (2/CU) + unroll-2 for load latency.
//  - 3 transpose launches merged into 1 (transpose_cvt3).
//  - softmax widened to 1024 threads (3 serial iters/pass instead of 10).
//  - GEMMs unchanged from round 7 (counted-vmcnt 3-buffer pipeline).
// Known fixed overhead: harness workspace re-poison fill = ~197us/iter (1.31GB).

typedef __bf16 bf16;
typedef __attribute__((ext_vector_type(8))) __bf16 bf16x8;
typedef __attribute__((ext_vector_type(4))) float f32x4;

#define AS1 __attribute__((address_space(1)))
#define AS3 __attribute__((address_space(3)))

#define WAITVM(N) asm volatile("s_waitcnt vmcnt(" #N ")" ::: "memory")
#define WAITLGKM0 asm volatile("s_waitcnt lgkmcnt(0)" ::: "memory")

// ---------------------------------------------------------------------------
// fragment read: 8 contiguous bf16 (16B) = global k-chunk kc of LDS row `row`
// (XOR chunk swizzle: LDS slot c holds global chunk c ^ (row&7))
// ---------------------------------------------------------------------------
__device__ __forceinline__ bf16x8 fragld(const bf16* s, int row, int kc) {
  const int c = kc ^ (row & 7);
  return *(const bf16x8*)(s + row * 64 + c * 8);
}

// ---------------------------------------------------------------------------
// async DMA staging (512 threads): ROWSx64 bf16 tile, XOR-swizzled.
// per wave dest = uniform base + lane*16B (required by global_load_lds).
// ---------------------------------------------------------------------------
template <int ROWS>
__device__ __forceinline__ void stage_dma(const bf16* __restrict__ g, size_t row0,
                                          int ld, int kb, bf16* s, int t) {
#pragma unroll
  for (int i = 0; i < ROWS / 64; ++i) {
    const int r  = i * 64 + (t >> 3);
    const int c  = t & 7;
    const int cg = c ^ (r & 7);
    const bf16* gp = g + (row0 + (size_t)r) * (size_t)ld + (size_t)(kb + cg * 8);
    bf16* sp = s + i * 4096 + t * 8;
    __builtin_amdgcn_global_load_lds((const AS1 void*)gp, (AS3 void*)sp, 16, 0, 0);
  }
}

// inline-asm f32x4 load: invisible to the compiler's waitcnt pass, so our
// counted WAITVM covers it (compiler would otherwise insert vmcnt(0)).
__device__ __forceinline__ float4 gload4(const float* p) {
  float4 r;
  asm volatile("global_load_dwordx4 %0, %1, off" : "=v"(r) : "v"(p) : "memory");
  return r;
}

// ---------------------------------------------------------------------------
// 32x32 tiled transpose f32 -> bf16, 3 weight matrices in one launch.
// z=0: W_enc [1024,512] -> WencT [512,1024]; z=1/2: W_u/W_v [512,512].
// ---------------------------------------------------------------------------
__global__ void transpose_cvt3(const float* __restrict__ W_enc,
                               const float* __restrict__ W_u,
                               const float* __restrict__ W_v,
                               bf16* __restrict__ WencT,
                               bf16* __restrict__ WuT,
                               bf16* __restrict__ WvT) {
  __shared__ float tile[32][33];
  const int z = blockIdx.z;
  const float* in = (z == 0) ? W_enc : (z == 1) ? W_u : W_v;
  bf16* out = (z == 0) ? WencT : (z == 1) ? WuT : WvT;
  const int R = (z == 0) ? 1024 : 512;
  const int C = 512;
  const int by = blockIdx.y * 32;  // row
  if (by >= R) return;
  const int bx = blockIdx.x * 32;  // col
  const int tx = threadIdx.x, ty = threadIdx.y;  // (32,8)
#pragma unroll
  for (int i = 0; i < 32; i += 8) tile[ty + i][tx] = in[(size_t)(by + ty + i) * C + bx + tx];
  __syncthreads();
#pragma unroll
  for (int i = 0; i < 32; i += 8) out[(size_t)(bx + ty + i) * R + by + tx] = (bf16)tile[tx][ty + i];
}

// ---------------------------------------------------------------------------
// GEMM1: emb = relu(bags[80000,1024](f32) @ W_enc + b_enc) -> bf16 [80000,512]
// Bt = W_enc^T bf16 [512,1024]. Tile 128x256, BK=64, 16 K-steps, 512 threads
// (8 waves: wm row-half, wn 64-col strip; acc 4x4). 3-buffer counted-vmcnt
// pipeline: per iter issue A(s+3) f32->regs (asm), B(s+2) via global_load_lds,
// cvt+ds_write A(s+1); steady wait = vmcnt(8).
// ---------------------------------------------------------------------------
__global__ __launch_bounds__(512, 2) void gemm_enc(const float* __restrict__ A,
                                                   const bf16* __restrict__ Bt,
                                                   const float* __restrict__ bias,
                                                   bf16* __restrict__ Cout) {
  __shared__ bf16 smem[3 * 24576];  // 3 bufs x [A 128x64 | B 256x64] = 144 KB
  const int t = threadIdx.x;
  const int lane = t & 63, wave = t >> 6;
  const int wm = wave >> 2, wn = wave & 3;
  // bijective XCD swizzle (nwg=1250, q=156, r=2): blocks (2k,2k+1) -> same XCD,
  // so the shared 512KB A-tile's 2nd read is an L2 hit.
  const int bid = blockIdx.x;
  const int xcd = bid & 7, idx = bid >> 3;
  const int wg  = (xcd < 2 ? xcd * 157 : 314 + (xcd - 2) * 156) + idx;
  const size_t m0 = (size_t)(wg >> 1) * 128;
  const int n0 = (wg & 1) * 256;
  const int lm = lane & 15, lq = lane >> 4;

  // A f32 address bases: row r = i*64 + (t>>3), chunk cg = (t&7) ^ (r&7)
  const int ar0 = t >> 3, ac = t & 7;
  const float* aB0 = A + (m0 + (size_t)ar0) * 1024 + (size_t)((ac ^ (ar0 & 7)) * 8);
  const float* aB1 = aB0 + (size_t)64 * 1024;  // (64+r)&7 == r&7

  f32x4 acc[4][4];
#pragma unroll
  for (int i = 0; i < 4; ++i)
#pragma unroll
    for (int j = 0; j < 4; ++j) acc[i][j] = f32x4{0.f, 0.f, 0.f, 0.f};

  float4 pv[3][4];

#define LDA(kb, slot)                              \
  do {                                             \
    pv[slot][0] = gload4(aB0 + (kb));              \
    pv[slot][1] = gload4(aB0 + (kb) + 4);          \
    pv[slot][2] = gload4(aB1 + (kb));              \
    pv[slot][3] = gload4(aB1 + (kb) + 4);          \
  } while (0)

#define CVTW(bufA, slot)                                              \
  do {                                                                \
    bf16x8 w0, w1;                                                    \
    w0[0] = (bf16)pv[slot][0].x; w0[1] = (bf16)pv[slot][0].y;         \
    w0[2] = (bf16)pv[slot][0].z; w0[3] = (bf16)pv[slot][0].w;         \
    w0[4] = (bf16)pv[slot][1].x; w0[5] = (bf16)pv[slot][1].y;         \
    w0[6] = (bf16)pv[slot][1].z; w0[7] = (bf16)pv[slot][1].w;         \
    w1[0] = (bf16)pv[slot][2].x; w1[1] = (bf16)pv[slot][2].y;         \
    w1[2] = (bf16)pv[slot][2].z; w1[3] = (bf16)pv[slot][2].w;         \
    w1[4] = (bf16)pv[slot][3].x; w1[5] = (bf16)pv[slot][3].y;         \
    w1[6] = (bf16)pv[slot][3].z; w1[7] = (bf16)pv[slot][3].w;         \
    *(bf16x8*)((bufA) + t * 8) = w0;                                  \
    *(bf16x8*)((bufA) + 4096 + t * 8) = w1;                           \
  } while (0)

  // prologue: A(0),B(0),A(1),B(1),A(2) issued; cvt A(0) -> buf0
  LDA(0, 0);
  stage_dma<256>(Bt, (size_t)n0, 1024, 0, smem + 8192, t);
  LDA(64, 1);
  stage_dma<256>(Bt, (size_t)n0, 1024, 64, smem + 24576 + 8192, t);
  LDA(128, 2);
  WAITVM(12);  // A(0) done
  CVTW(smem, 0);

#pragma unroll
  for (int s = 0; s < 16; ++s) {
    if (s <= 13) { WAITVM(8); }       // A(s+1), B(s) done; A(s+2),B(s+1) in flight
    else if (s == 14) { WAITVM(4); }  // tail: only B(15) may remain
    else { WAITVM(0); }
    WAITLGKM0;                        // publish my ds_writes before barrier
    __builtin_amdgcn_s_barrier();
    __builtin_amdgcn_sched_barrier(0);
    bf16* bufc = smem + (s % 3) * 24576;
    if (s < 15) CVTW(smem + ((s + 1) % 3) * 24576, (s + 1) % 3);
    if (s < 13) LDA((s + 3) * 64, (s + 3) % 3);
    if (s < 14) stage_dma<256>(Bt, (size_t)n0, 1024, (s + 2) * 64,
                               smem + ((s + 2) % 3) * 24576 + 8192, t);
    const bf16* sA = bufc;
    const bf16* sB = bufc + 8192;
#pragma unroll
    for (int kk = 0; kk < 2; ++kk) {
      bf16x8 af[4];
#pragma unroll
      for (int mi = 0; mi < 4; ++mi) af[mi] = fragld(sA, wm * 64 + mi * 16 + lm, kk * 4 + lq);
#pragma unroll
      for (int ni = 0; ni < 4; ++ni) {
        const bf16x8 bfr = fragld(sB, wn * 64 + ni * 16 + lm, kk * 4 + lq);
#pragma unroll
        for (int mi = 0; mi < 4; ++mi)
          acc[mi][ni] = __builtin_amdgcn_mfma_f32_16x16x32_bf16(af[mi], bfr, acc[mi][ni], 0, 0, 0);
      }
    }
  }
#undef LDA
#undef CVTW

  // epilogue: bias + relu, store bf16. D layout: col=lane&15, row=lq*4+reg.
#pragma unroll
  for (int ni = 0; ni < 4; ++ni) {
    const int n_g = n0 + wn * 64 + ni * 16 + lm;
    const float bz = bias[n_g];
#pragma unroll
    for (int mi = 0; mi < 4; ++mi) {
#pragma unroll
      for (int r = 0; r < 4; ++r) {
        const size_t m_g = m0 + (size_t)(wm * 64 + mi * 16 + lq * 4 + r);
        const float v = acc[mi][ni][r] + bz;
        Cout[m_g * 512 + n_g] = (bf16)fmaxf(v, 0.f);
      }
    }
  }
}

// ---------------------------------------------------------------------------
// GEMM2 (fused gate + attention logits), atomic-free, counted-vmcnt:
//   hu = emb@W_u + b_u ; hv = emb@W_v + b_v ; g = sigmoid(hu)*tanh(hv)
//   logitsT[c][m] = sum_z g[m,z] * W_attn[c,z]
// Block owns 128 rows; 4 z-chunks x 8 K-steps = 32 steps, 3-buffer rotation,
// stage(s+2) per iter, steady wait vmcnt(6). Epilogue consts live in LDS.
// ---------------------------------------------------------------------------
__global__ __launch_bounds__(512, 2) void gemm_gate(const bf16* __restrict__ A,
                                                    const bf16* __restrict__ But,
                                                    const bf16* __restrict__ Bvt,
                                                    const float* __restrict__ bu,
                                                    const float* __restrict__ bv,
                                                    const float* __restrict__ Wa,
                                                    float* __restrict__ logitsT) {
  // 3 x [sA 128x64 | sU 128x64 | sV 128x64] (144KB) + consts 12KB = 156KB
  __shared__ bf16 smem[3 * 24576 + 6144];
  float* sBu = (float*)(smem + 73728);
  float* sBv = sBu + 512;
  float* sWa = sBv + 512;  // 2048 floats, layout [c][z]
  const int t = threadIdx.x;
  const int lane = t & 63, wave = t >> 6;
  const int wm = wave >> 2, wn = wave & 3;
  const size_t m0 = (size_t)blockIdx.x * 128;
  const int lm = lane & 15, lq = lane >> 4;

  // preload epilogue consts into LDS (before any DMA issues)
  sBu[t] = bu[t];
  sBv[t] = bv[t];
  ((float4*)sWa)[t] = ((const float4*)Wa)[t];

  f32x4 accU[4][2], accV[4][2];
  float pc[4][4][4];  // [mi][r][c] per-lane partial logits
#pragma unroll
  for (int mi = 0; mi < 4; ++mi)
#pragma unroll
    for (int r = 0; r < 4; ++r)
#pragma unroll
      for (int c = 0; c < 4; ++c) pc[mi][r][c] = 0.f;

  // prologue: stage steps 0 and 1
  stage_dma<128>(A,   m0, 512, 0, smem, t);
  stage_dma<128>(But, 0,  512, 0, smem + 8192, t);
  stage_dma<128>(Bvt, 0,  512, 0, smem + 16384, t);
  stage_dma<128>(A,   m0, 512, 64, smem + 24576, t);
  stage_dma<128>(But, 0,  512, 64, smem + 24576 + 8192, t);
  stage_dma<128>(Bvt, 0,  512, 64, smem + 24576 + 16384, t);

  for (int s = 0; s < 32; ++s) {
    if ((s & 7) == 0) {
#pragma unroll
      for (int i = 0; i < 4; ++i)
#pragma unroll
        for (int j = 0; j < 2; ++j) {
          accU[i][j] = f32x4{0.f, 0.f, 0.f, 0.f};
          accV[i][j] = f32x4{0.f, 0.f, 0.f, 0.f};
        }
    }
    if (s == 31) { WAITVM(0); } else { WAITVM(6); }  // stage(s) done, stage(s+1) in flight
    WAITLGKM0;  // publish const ds_writes (iter 0); later iters free
    __builtin_amdgcn_s_barrier();
    __builtin_amdgcn_sched_barrier(0);
    const bf16* base = smem + (s % 3) * 24576;
    if (s < 30) {  // stage step s+2 into the buffer freed by iter s-1
      const int st = s + 2, nc1 = st >> 3, kb1 = (st & 7) << 6;
      bf16* nb = smem + (st % 3) * 24576;
      stage_dma<128>(A,   m0,                  512, kb1, nb, t);
      stage_dma<128>(But, (size_t)(nc1 * 128), 512, kb1, nb + 8192, t);
      stage_dma<128>(Bvt, (size_t)(nc1 * 128), 512, kb1, nb + 16384, t);
    }
#pragma unroll
    for (int kk = 0; kk < 2; ++kk) {
      bf16x8 af[4];
#pragma unroll
      for (int mi = 0; mi < 4; ++mi) af[mi] = fragld(base, wm * 64 + mi * 16 + lm, kk * 4 + lq);
#pragma unroll
      for (int ni = 0; ni < 2; ++ni) {
        const int row = wn * 32 + ni * 16 + lm;
        const bf16x8 bu8 = fragld(base + 8192,  row, kk * 4 + lq);
        const bf16x8 bv8 = fragld(base + 16384, row, kk * 4 + lq);
#pragma unroll
        for (int mi = 0; mi < 4; ++mi)
          accU[mi][ni] = __builtin_amdgcn_mfma_f32_16x16x32_bf16(af[mi], bu8, accU[mi][ni], 0, 0, 0);
#pragma unroll
        for (int mi = 0; mi < 4; ++mi)
          accV[mi][ni] = __builtin_amdgcn_mfma_f32_16x16x32_bf16(af[mi], bv8, accV[mi][ni], 0, 0, 0);
      }
    }
    if ((s & 7) == 7) {
      // nonlinearity + W_attn contraction for this z-chunk (consts from LDS)
      const int nc = s >> 3;
#pragma unroll
      for (int ni = 0; ni < 2; ++ni) {
        const int n_g = nc * 128 + wn * 32 + ni * 16 + lm;
        const float bzu = sBu[n_g], bzv = sBv[n_g];
        float wac[4];
#pragma unroll
        for (int c = 0; c < 4; ++c) wac[c] = sWa[c * 512 + n_g];
#pragma unroll
        for (int mi = 0; mi < 4; ++mi) {
#pragma unroll
          for (int r = 0; r < 4; ++r) {
            const float hu = accU[mi][ni][r] + bzu;
            const float hv = accV[mi][ni][r] + bzv;
            const float sg = __builtin_amdgcn_rcpf(1.f + __expf(-hu));
            const float th = 1.f - 2.f * __builtin_amdgcn_rcpf(1.f + __expf(2.f * hv));
            const float g = sg * th;
#pragma unroll
            for (int c = 0; c < 4; ++c) pc[mi][r][c] += g * wac[c];
          }
        }
      }
    }
  }

  // reduce pc over the 16 lanes (lm bits) sharing each output row
#pragma unroll
  for (int mi = 0; mi < 4; ++mi)
#pragma unroll
    for (int r = 0; r < 4; ++r)
#pragma unroll
      for (int c = 0; c < 4; ++c) {
#pragma unroll
        for (int o = 8; o >= 1; o >>= 1) pc[mi][r][c] += __shfl_xor(pc[mi][r][c], o);
      }
  // red aliases buf0 space (safe: buf0 last read at s=30, barrier-protected)
  float (*red)[64][4] = (float (*)[64][4])smem;
  if (lm == 0) {
#pragma unroll
    for (int mi = 0; mi < 4; ++mi)
#pragma unroll
      for (int r = 0; r < 4; ++r)
#pragma unroll
        for (int c = 0; c < 4; ++c) red[wave][mi * 16 + lq * 4 + r][c] = pc[mi][r][c];
  }
  __syncthreads();
  // cross-wn sum + coalesced store: threads 0..127 -> c=0 rows m0..m0+127, etc.
  {
    const int row = t & 127, c = t >> 7;
    const int wmr = row >> 6, loc = row & 63;
    const float v = red[wmr * 4 + 0][loc][c] + red[wmr * 4 + 1][loc][c] +
                    red[wmr * 4 + 2][loc][c] + red[wmr * 4 + 3][loc][c];
    logitsT[(size_t)c * 80000 + m0 + row] = v;
  }
}

// ---------------------------------------------------------------------------
// softmax over N per (b,c) on logitsT [c][b][n] layout: 32 contiguous rows of
// 10000 floats. float4 passes, 1024 threads, in-place rewrite with attn.
// b_attn omitted: constant shift per (b,c) cancels in softmax.
// ---------------------------------------------------------------------------
__global__ __launch_bounds__(1024) void softmax_attn(float* __restrict__ logits) {
  float* base = logits + (size_t)blockIdx.x * 10000;
  float4* b4 = (float4*)base;
  const int t = threadIdx.x;
  const int lane = t & 63, w = t >> 6;
  __shared__ float red[32];

  float m = -3.0e38f;
  for (int i = t; i < 2500; i += 1024) {
    const float4 v = b4[i];
    m = fmaxf(m, fmaxf(fmaxf(v.x, v.y), fmaxf(v.z, v.w)));
  }
#pragma unroll
  for (int o = 32; o >= 1; o >>= 1) m = fmaxf(m, __shfl_xor(m, o));
  if (lane == 0) red[w] = m;
  __syncthreads();
#pragma unroll
  for (int i = 0; i < 16; ++i) m = fmaxf(m, red[i]);

  float s = 0.f;
  for (int i = t; i < 2500; i += 1024) {
    const float4 v = b4[i];
    s += __expf(v.x - m) + __expf(v.y - m) + __expf(v.z - m) + __expf(v.w - m);
  }
#pragma unroll
  for (int o = 32; o >= 1; o >>= 1) s += __shfl_xor(s, o);
  if (lane == 0) red[16 + w] = s;
  __syncthreads();
  s = 0.f;
#pragma unroll
  for (int i = 0; i < 16; ++i) s += red[16 + i];

  const float rs = 1.f / s;
  for (int i = t; i < 2500; i += 1024) {
    float4 v = b4[i];
    v.x = __expf(v.x - m) * rs;
    v.y = __expf(v.y - m) * rs;
    v.z = __expf(v.z - m) * rs;
    v.w = __expf(v.w - m) * rs;
    b4[i] = v;
  }
}

// ---------------------------------------------------------------------------
// scores[b,c] = sum_z reps[b,c,z] * Wcls[c,z], reps = sum_n attn[c,b,n]*emb[b,n,z].
// Shuffle-free main loop: lane owns z-slice [lane*8, lane*8+8); acc[c][j]
// accumulates attn-weighted emb. One dot+reduce per block at the end.
// grid (8 bags, 64 chunks of 157 rows), 256 threads (4 waves, row round-robin).
// ---------------------------------------------------------------------------
__global__ __launch_bounds__(256) void scores_partial(const bf16* __restrict__ emb,
                                                      const float* __restrict__ attn,
                                                      const float* __restrict__ Wcls,
                                                      float* __restrict__ sacc) {
  const int b = blockIdx.x;
  const int chunk = blockIdx.y;
  const int t = threadIdx.x;
  const int wave = t >> 6, lane = t & 63;

  float wcl[4][8];
#pragma unroll
  for (int c = 0; c < 4; ++c) {
    const float4 wlo = *(const float4*)(Wcls + c * 512 + lane * 8);
    const float4 whi = *(const float4*)(Wcls + c * 512 + lane * 8 + 4);
    wcl[c][0] = wlo.x; wcl[c][1] = wlo.y; wcl[c][2] = wlo.z; wcl[c][3] = wlo.w;
    wcl[c][4] = whi.x; wcl[c][5] = whi.y; wcl[c][6] = whi.z; wcl[c][7] = whi.w;
  }

  float acc[4][8];
#pragma unroll
  for (int c = 0; c < 4; ++c)
#pragma unroll
    for (int j = 0; j < 8; ++j) acc[c][j] = 0.f;

  const int nbeg = chunk * 157;
  const int nend = (nbeg + 157 < 10000) ? nbeg + 157 : 10000;
  for (int n = nbeg + wave; n < nend; n += 8) {
    // unroll-2: rows n and n+4 (this wave's next), loads issued up front
    const size_t row0 = (size_t)b * 10000 + n;
    const bf16x8 e0 = *(const bf16x8*)(emb + row0 * 512 + lane * 8);
    float w0[4];
#pragma unroll
    for (int c = 0; c < 4; ++c) w0[c] = attn[(size_t)c * 80000 + row0];
    const int n1 = n + 4;
    const bool v1 = (n1 < nend);
    bf16x8 e1;
    float w1[4];
    if (v1) {
      const size_t row1 = row0 + 4;
      e1 = *(const bf16x8*)(emb + row1 * 512 + lane * 8);
#pragma unroll
      for (int c = 0; c < 4; ++c) w1[c] = attn[(size_t)c * 80000 + row1];
    }
#pragma unroll
    for (int j = 0; j < 8; ++j) {
      const float e = (float)e0[j];
#pragma unroll
      for (int c = 0; c < 4; ++c) acc[c][j] += w0[c] * e;
    }
    if (v1) {
#pragma unroll
      for (int j = 0; j < 8; ++j) {
        const float e = (float)e1[j];
#pragma unroll
        for (int c = 0; c < 4; ++c) acc[c][j] += w1[c] * e;
      }
    }
  }

  // dot with Wcls, then ONE reduction per block
  float p[4];
#pragma unroll
  for (int c = 0; c < 4; ++c) {
    p[c] = 0.f;
#pragma unroll
    for (int j = 0; j < 8; ++j) p[c] += acc[c][j] * wcl[c][j];
  }
#pragma unroll
  for (int o = 32; o >= 1; o >>= 1) {
#pragma unroll
    for (int c = 0; c < 4; ++c) p[c] += __shfl_xor(p[c], o);
  }
  __shared__ float lred[4][4];
  if (lane == 0) {
#pragma unroll
    for (int c = 0; c < 4; ++c) lred[wave][c] = p[c];
  }
  __syncthreads();
  if (t < 4) {
    atomicAdd(&sacc[b * 4 + t], lred[0][t] + lred[1][t] + lred[2][t] + lred[3][t]);
  }
}

__global__ void finalize(const float* __restrict__ sacc, const float* __restrict__ b_cls,
                         float* __restrict__ out) {
  const int i = threadIdx.x;
  if (i < 32) out[i] = sacc[i] + b_cls[i & 3];
}

// ---------------------------------------------------------------------------
extern "C" void kernel_launch(void* const* d_in, const int* in_sizes, int n_in,
                              void* d_out, int out_size, void* d_ws, size_t ws_size,
                              hipStream_t stream) {
  (void)in_sizes; (void)n_in; (void)out_size; (void)ws_size;
  const float* bags   = (const float*)d_in[0];
  const float* W_enc  = (const float*)d_in[1];
  const float* b_enc  = (const float*)d_in[2];
  const float* W_u    = (const float*)d_in[3];
  const float* b_u    = (const float*)d_in[4];
  const float* W_v    = (const float*)d_in[5];
  const float* b_v    = (const float*)d_in[6];
  const float* W_attn = (const float*)d_in[7];
  // d_in[8] = b_attn: unused (cancels in softmax over instances)
  const float* W_cls  = (const float*)d_in[9];
  const float* b_cls  = (const float*)d_in[10];
  float* out = (float*)d_out;

  char* ws = (char*)d_ws;
  bf16*  emb     = (bf16*)(ws);                      // 80000*512*2  = 81,920,000 B
  float* logitsT = (float*)(ws + 81920000);          // 4*80000*4   =  1,280,000 B
  bf16*  WencT   = (bf16*)(ws + 83200000);           // 512*1024*2  =  1,048,576 B
  bf16*  WuT     = (bf16*)(ws + 84248576);           // 512*512*2   =    524,288 B
  bf16*  WvT     = (bf16*)(ws + 84772864);           // 512*512*2   =    524,288 B
  float* sacc    = (float*)(ws + 85297152);          // 32*4        =        128 B

  hipMemsetAsync(sacc, 0, 32 * sizeof(float), stream);

  transpose_cvt3<<<dim3(16, 32, 3), dim3(32, 8), 0, stream>>>(W_enc, W_u, W_v,
                                                              WencT, WuT, WvT);

  gemm_enc<<<1250, 512, 0, stream>>>(bags, WencT, b_enc, emb);
  gemm_gate<<<625, 512, 0, stream>>>(emb, WuT, WvT, b_u, b_v, W_attn, logitsT);
  softmax_attn<<<32, 1024, 0, stream>>>(logitsT);
  scores_partial<<<dim3(8, 64), 256, 0, stream>>>(emb, logitsT, W_cls, sacc);
  finalize<<<1, 64, 0, stream>>>(sacc, b_cls, out);
}

// Round 5
// 650.671 us; speedup vs baseline: 1.3040x; 1.0083x over previous
//
#include <hip/hip_runtime.h>
#include <hip/hip_bf16.h>
#include <cstdint>

// CLAM-MIL forward. Inputs/outputs FLOAT32; internal compute bf16 MFMA + fp32 accum.
// B=8, N=10000 (M=80000 rows), F=1024, Z=512, C=4.
//
// Round 10 (= R9 resubmit with VGPR fix). Gate: 2 blocks/CU (77.8KB LDS),
// wave tile now 32 rows x 32 cols (was 64x16) -> pc shrinks 64->32 regs,
// total ~110 VGPR < launch_bounds(512,4) cap of 128 -> no spills.
// 64 steps (8 nc x 8 kb) of 16 MFMA, plain dbuf + __syncthreads (cross-block
// TLP covers the drain, m97 regime). T5 setprio around MFMA clusters.
// enc unchanged (3-buffer counted-vmcnt). Known fixed: ~196us re-poison fill.

typedef __bf16 bf16;
typedef __attribute__((ext_vector_type(8))) __bf16 bf16x8;
typedef __attribute__((ext_vector_type(4))) float f32x4;

#define AS1 __attribute__((address_space(1)))
#define AS3 __attribute__((address_space(3)))

#define WAITVM(N) asm volatile("s_waitcnt vmcnt(" #N ")" ::: "memory")
#define WAITLGKM0 asm volatile("s_waitcnt lgkmcnt(0)" ::: "memory")

// ---------------------------------------------------------------------------
// fragment read: 8 contiguous bf16 (16B) = global k-chunk kc of LDS row `row`
// (XOR chunk swizzle: LDS slot c holds global chunk c ^ (row&7))
// ---------------------------------------------------------------------------
__device__ __forceinline__ bf16x8 fragld(const bf16* s, int row, int kc) {
  const int c = kc ^ (row & 7);
  return *(const bf16x8*)(s + row * 64 + c * 8);
}

// ---------------------------------------------------------------------------
// async DMA staging (512 threads): ROWSx64 bf16 tile, XOR-swizzled.
// per wave dest = uniform base + lane*16B (required by global_load_lds).
// ---------------------------------------------------------------------------
template <int ROWS>
__device__ __forceinline__ void stage_dma(const bf16* __restrict__ g, size_t row0,
                                          int ld, int kb, bf16* s, int t) {
#pragma unroll
  for (int i = 0; i < ROWS / 64; ++i) {
    const int r  = i * 64 + (t >> 3);
    const int c  = t & 7;
    const int cg = c ^ (r & 7);
    const bf16* gp = g + (row0 + (size_t)r) * (size_t)ld + (size_t)(kb + cg * 8);
    bf16* sp = s + i * 4096 + t * 8;
    __builtin_amdgcn_global_load_lds((const AS1 void*)gp, (AS3 void*)sp, 16, 0, 0);
  }
}

// inline-asm f32x4 load: invisible to the compiler's waitcnt pass, so our
// counted WAITVM covers it (compiler would otherwise insert vmcnt(0)).
__device__ __forceinline__ float4 gload4(const float* p) {
  float4 r;
  asm volatile("global_load_dwordx4 %0, %1, off" : "=v"(r) : "v"(p) : "memory");
  return r;
}

// ---------------------------------------------------------------------------
// 32x32 tiled transpose f32 -> bf16, 3 weight matrices in one launch.
// z=0: W_enc [1024,512] -> WencT [512,1024]; z=1/2: W_u/W_v [512,512].
// ---------------------------------------------------------------------------
__global__ void transpose_cvt3(const float* __restrict__ W_enc,
                               const float* __restrict__ W_u,
                               const float* __restrict__ W_v,
                               bf16* __restrict__ WencT,
                               bf16* __restrict__ WuT,
                               bf16* __restrict__ WvT) {
  __shared__ float tile[32][33];
  const int z = blockIdx.z;
  const float* in = (z == 0) ? W_enc : (z == 1) ? W_u : W_v;
  bf16* out = (z == 0) ? WencT : (z == 1) ? WuT : WvT;
  const int R = (z == 0) ? 1024 : 512;
  const int C = 512;
  const int by = blockIdx.y * 32;  // row
  if (by >= R) return;
  const int bx = blockIdx.x * 32;  // col
  const int tx = threadIdx.x, ty = threadIdx.y;  // (32,8)
#pragma unroll
  for (int i = 0; i < 32; i += 8) tile[ty + i][tx] = in[(size_t)(by + ty + i) * C + bx + tx];
  __syncthreads();
#pragma unroll
  for (int i = 0; i < 32; i += 8) out[(size_t)(bx + ty + i) * R + by + tx] = (bf16)tile[tx][ty + i];
}

// ---------------------------------------------------------------------------
// GEMM1: emb = relu(bags[80000,1024](f32) @ W_enc + b_enc) -> bf16 [80000,512]
// Bt = W_enc^T bf16 [512,1024]. Tile 128x256, BK=64, 16 K-steps, 512 threads
// (8 waves: wm row-half, wn 64-col strip; acc 4x4). 3-buffer counted-vmcnt
// pipeline: per iter issue A(s+3) f32->regs (asm), B(s+2) via global_load_lds,
// cvt+ds_write A(s+1); steady wait = vmcnt(8).
// ---------------------------------------------------------------------------
__global__ __launch_bounds__(512, 2) void gemm_enc(const float* __restrict__ A,
                                                   const bf16* __restrict__ Bt,
                                                   const float* __restrict__ bias,
                                                   bf16* __restrict__ Cout) {
  __shared__ bf16 smem[3 * 24576];  // 3 bufs x [A 128x64 | B 256x64] = 144 KB
  const int t = threadIdx.x;
  const int lane = t & 63, wave = t >> 6;
  const int wm = wave >> 2, wn = wave & 3;
  // bijective XCD swizzle (nwg=1250, q=156, r=2): blocks (2k,2k+1) -> same XCD,
  // so the shared 512KB A-tile's 2nd read is an L2 hit.
  const int bid = blockIdx.x;
  const int xcd = bid & 7, idx = bid >> 3;
  const int wg  = (xcd < 2 ? xcd * 157 : 314 + (xcd - 2) * 156) + idx;
  const size_t m0 = (size_t)(wg >> 1) * 128;
  const int n0 = (wg & 1) * 256;
  const int lm = lane & 15, lq = lane >> 4;

  // A f32 address bases: row r = i*64 + (t>>3), chunk cg = (t&7) ^ (r&7)
  const int ar0 = t >> 3, ac = t & 7;
  const float* aB0 = A + (m0 + (size_t)ar0) * 1024 + (size_t)((ac ^ (ar0 & 7)) * 8);
  const float* aB1 = aB0 + (size_t)64 * 1024;  // (64+r)&7 == r&7

  f32x4 acc[4][4];
#pragma unroll
  for (int i = 0; i < 4; ++i)
#pragma unroll
    for (int j = 0; j < 4; ++j) acc[i][j] = f32x4{0.f, 0.f, 0.f, 0.f};

  float4 pv[3][4];

#define LDA(kb, slot)                              \
  do {                                             \
    pv[slot][0] = gload4(aB0 + (kb));              \
    pv[slot][1] = gload4(aB0 + (kb) + 4);          \
    pv[slot][2] = gload4(aB1 + (kb));              \
    pv[slot][3] = gload4(aB1 + (kb) + 4);          \
  } while (0)

#define CVTW(bufA, slot)                                              \
  do {                                                                \
    bf16x8 w0, w1;                                                    \
    w0[0] = (bf16)pv[slot][0].x; w0[1] = (bf16)pv[slot][0].y;         \
    w0[2] = (bf16)pv[slot][0].z; w0[3] = (bf16)pv[slot][0].w;         \
    w0[4] = (bf16)pv[slot][1].x; w0[5] = (bf16)pv[slot][1].y;         \
    w0[6] = (bf16)pv[slot][1].z; w0[7] = (bf16)pv[slot][1].w;         \
    w1[0] = (bf16)pv[slot][2].x; w1[1] = (bf16)pv[slot][2].y;         \
    w1[2] = (bf16)pv[slot][2].z; w1[3] = (bf16)pv[slot][2].w;         \
    w1[4] = (bf16)pv[slot][3].x; w1[5] = (bf16)pv[slot][3].y;         \
    w1[6] = (bf16)pv[slot][3].z; w1[7] = (bf16)pv[slot][3].w;         \
    *(bf16x8*)((bufA) + t * 8) = w0;                                  \
    *(bf16x8*)((bufA) + 4096 + t * 8) = w1;                           \
  } while (0)

  // prologue: A(0),B(0),A(1),B(1),A(2) issued; cvt A(0) -> buf0
  LDA(0, 0);
  stage_dma<256>(Bt, (size_t)n0, 1024, 0, smem + 8192, t);
  LDA(64, 1);
  stage_dma<256>(Bt, (size_t)n0, 1024, 64, smem + 24576 + 8192, t);
  LDA(128, 2);
  WAITVM(12);  // A(0) done
  CVTW(smem, 0);

#pragma unroll
  for (int s = 0; s < 16; ++s) {
    if (s <= 13) { WAITVM(8); }       // A(s+1), B(s) done; A(s+2),B(s+1) in flight
    else if (s == 14) { WAITVM(4); }  // tail: only B(15) may remain
    else { WAITVM(0); }
    WAITLGKM0;                        // publish my ds_writes before barrier
    __builtin_amdgcn_s_barrier();
    __builtin_amdgcn_sched_barrier(0);
    bf16* bufc = smem + (s % 3) * 24576;
    if (s < 15) CVTW(smem + ((s + 1) % 3) * 24576, (s + 1) % 3);
    if (s < 13) LDA((s + 3) * 64, (s + 3) % 3);
    if (s < 14) stage_dma<256>(Bt, (size_t)n0, 1024, (s + 2) * 64,
                               smem + ((s + 2) % 3) * 24576 + 8192, t);
    const bf16* sA = bufc;
    const bf16* sB = bufc + 8192;
    __builtin_amdgcn_s_setprio(1);
#pragma unroll
    for (int kk = 0; kk < 2; ++kk) {
      bf16x8 af[4];
#pragma unroll
      for (int mi = 0; mi < 4; ++mi) af[mi] = fragld(sA, wm * 64 + mi * 16 + lm, kk * 4 + lq);
#pragma unroll
      for (int ni = 0; ni < 4; ++ni) {
        const bf16x8 bfr = fragld(sB, wn * 64 + ni * 16 + lm, kk * 4 + lq);
#pragma unroll
        for (int mi = 0; mi < 4; ++mi)
          acc[mi][ni] = __builtin_amdgcn_mfma_f32_16x16x32_bf16(af[mi], bfr, acc[mi][ni], 0, 0, 0);
      }
    }
    __builtin_amdgcn_s_setprio(0);
  }
#undef LDA
#undef CVTW

  // epilogue: bias + relu, store bf16. D layout: col=lane&15, row=lq*4+reg.
#pragma unroll
  for (int ni = 0; ni < 4; ++ni) {
    const int n_g = n0 + wn * 64 + ni * 16 + lm;
    const float bz = bias[n_g];
#pragma unroll
    for (int mi = 0; mi < 4; ++mi) {
#pragma unroll
      for (int r = 0; r < 4; ++r) {
        const size_t m_g = m0 + (size_t)(wm * 64 + mi * 16 + lq * 4 + r);
        const float v = acc[mi][ni][r] + bz;
        Cout[m_g * 512 + n_g] = (bf16)fmaxf(v, 0.f);
      }
    }
  }
}

// ---------------------------------------------------------------------------
// GEMM2 (fused gate + attention logits), atomic-free, 2 blocks/CU:
//   hu = emb@W_u + b_u ; hv = emb@W_v + b_v ; g = sigmoid(hu)*tanh(hv)
//   logitsT[c][m] = sum_z g[m,z] * W_attn[c,z]
// Block owns 128 rows; 8 z-chunks of 64 x 8 K-steps = 64 steps. Per-step
// buffer = A(128x64) + U(64x64) + V(64x64) = 32KB; 2 bufs + 12KB consts =
// 77.8KB -> 2 resident blocks/CU (16 waves). 8 waves: wm{0..3} 32-row quarter
// x wn{0,1} 32-col strip; wave = 32x32 of BOTH U and V (accU/accV 2x2 = 32
// regs, pc[2][4][4] = 32 regs -> ~110 VGPR, fits the 128 cap of (512,4)).
// ---------------------------------------------------------------------------
__global__ __launch_bounds__(512, 4) void gemm_gate(const bf16* __restrict__ A,
                                                    const bf16* __restrict__ But,
                                                    const bf16* __restrict__ Bvt,
                                                    const float* __restrict__ bu,
                                                    const float* __restrict__ bv,
                                                    const float* __restrict__ Wa,
                                                    float* __restrict__ logitsT) {
  // 2 bufs x [A 128x64 | U 64x64 | V 64x64] (64KB) + consts 12KB = 77.8KB
  __shared__ bf16 smem[2 * 16384 + 6144];
  float* sBu = (float*)(smem + 32768);
  float* sBv = sBu + 512;
  float* sWa = sBv + 512;  // 2048 floats, layout [c][z]
  const int t = threadIdx.x;
  const int lane = t & 63, wave = t >> 6;
  const int wm = wave >> 1, wn = wave & 1;  // 4 row-quarters x 2 col-strips
  const size_t m0 = (size_t)blockIdx.x * 128;
  const int lm = lane & 15, lq = lane >> 4;

  // preload epilogue consts into LDS (published by first __syncthreads)
  sBu[t] = bu[t];
  sBv[t] = bv[t];
  ((float4*)sWa)[t] = ((const float4*)Wa)[t];

  f32x4 accU[2][2], accV[2][2];
  float pc[2][4][4];  // [mi][r][c] per-lane partial logits (32 regs)
#pragma unroll
  for (int mi = 0; mi < 2; ++mi)
#pragma unroll
    for (int r = 0; r < 4; ++r)
#pragma unroll
      for (int c = 0; c < 4; ++c) pc[mi][r][c] = 0.f;

  // prologue: stage step 0 into buf0
  stage_dma<128>(A,   m0, 512, 0, smem, t);
  stage_dma<64>(But,  0,  512, 0, smem + 8192, t);
  stage_dma<64>(Bvt,  0,  512, 0, smem + 12288, t);

  for (int s = 0; s < 64; ++s) {
    if ((s & 7) == 0) {
#pragma unroll
      for (int i = 0; i < 2; ++i)
#pragma unroll
        for (int j = 0; j < 2; ++j) {
          accU[i][j] = f32x4{0.f, 0.f, 0.f, 0.f};
          accV[i][j] = f32x4{0.f, 0.f, 0.f, 0.f};
        }
    }
    __syncthreads();  // drains stage(s) (vmcnt0+lgkm0); buf (s+1)&1 free
    const bf16* base = smem + (s & 1) * 16384;
    if (s < 63) {  // prefetch next step into the other buffer
      const int st = s + 1, nc1 = st >> 3, kb1 = (st & 7) << 6;
      bf16* nb = smem + (st & 1) * 16384;
      stage_dma<128>(A,   m0,                 512, kb1, nb, t);
      stage_dma<64>(But,  (size_t)(nc1 * 64), 512, kb1, nb + 8192, t);
      stage_dma<64>(Bvt,  (size_t)(nc1 * 64), 512, kb1, nb + 12288, t);
    }
    __builtin_amdgcn_s_setprio(1);
#pragma unroll
    for (int kk = 0; kk < 2; ++kk) {
      bf16x8 af[2];
#pragma unroll
      for (int mi = 0; mi < 2; ++mi) af[mi] = fragld(base, wm * 32 + mi * 16 + lm, kk * 4 + lq);
#pragma unroll
      for (int ni = 0; ni < 2; ++ni) {
        const int urow = wn * 32 + ni * 16 + lm;
        const bf16x8 bu8 = fragld(base + 8192,  urow, kk * 4 + lq);
        const bf16x8 bv8 = fragld(base + 12288, urow, kk * 4 + lq);
#pragma unroll
        for (int mi = 0; mi < 2; ++mi)
          accU[mi][ni] = __builtin_amdgcn_mfma_f32_16x16x32_bf16(af[mi], bu8, accU[mi][ni], 0, 0, 0);
#pragma unroll
        for (int mi = 0; mi < 2; ++mi)
          accV[mi][ni] = __builtin_amdgcn_mfma_f32_16x16x32_bf16(af[mi], bv8, accV[mi][ni], 0, 0, 0);
      }
    }
    __builtin_amdgcn_s_setprio(0);
    if ((s & 7) == 7) {
      // nonlinearity + W_attn contraction for this 64-col z-chunk
      const int nc = s >> 3;
#pragma unroll
      for (int ni = 0; ni < 2; ++ni) {
        const int n_g = nc * 64 + wn * 32 + ni * 16 + lm;
        const float bzu = sBu[n_g], bzv = sBv[n_g];
        float wac[4];
#pragma unroll
        for (int c = 0; c < 4; ++c) wac[c] = sWa[c * 512 + n_g];
#pragma unroll
        for (int mi = 0; mi < 2; ++mi) {
#pragma unroll
          for (int r = 0; r < 4; ++r) {
            const float hu = accU[mi][ni][r] + bzu;
            const float hv = accV[mi][ni][r] + bzv;
            const float sg = __builtin_amdgcn_rcpf(1.f + __expf(-hu));
            const float th = 1.f - 2.f * __builtin_amdgcn_rcpf(1.f + __expf(2.f * hv));
            const float g = sg * th;
#pragma unroll
            for (int c = 0; c < 4; ++c) pc[mi][r][c] += g * wac[c];
          }
        }
      }
    }
  }

  // reduce pc over the 16 lanes (lm bits) sharing each output row
#pragma unroll
  for (int mi = 0; mi < 2; ++mi)
#pragma unroll
    for (int r = 0; r < 4; ++r)
#pragma unroll
      for (int c = 0; c < 4; ++c) {
#pragma unroll
        for (int o = 8; o >= 1; o >>= 1) pc[mi][r][c] += __shfl_xor(pc[mi][r][c], o);
      }
  // red aliases buf0 (4KB; all buf0 reads done: last buf0 read was step 62 and
  // every wave passed the top-of-step-63 barrier)
  float (*red)[32][4] = (float (*)[32][4])smem;
  if (lm == 0) {
#pragma unroll
    for (int mi = 0; mi < 2; ++mi)
#pragma unroll
      for (int r = 0; r < 4; ++r)
#pragma unroll
        for (int c = 0; c < 4; ++c) red[wave][mi * 16 + lq * 4 + r][c] = pc[mi][r][c];
  }
  __syncthreads();
  // cross-wn sum + coalesced store: threads 0..127 -> c=0 rows m0..m0+127, etc.
  {
    const int row = t & 127, c = t >> 7;
    const int wmr = row >> 5, loc = row & 31;
    const float v = red[wmr * 2 + 0][loc][c] + red[wmr * 2 + 1][loc][c];
    logitsT[(size_t)c * 80000 + m0 + row] = v;
  }
}

// ---------------------------------------------------------------------------
// softmax over N per (b,c) on logitsT [c][b][n] layout: 32 contiguous rows of
// 10000 floats. float4 passes, 1024 threads, in-place rewrite with attn.
// b_attn omitted: constant shift per (b,c) cancels in softmax.
// ---------------------------------------------------------------------------
__global__ __launch_bounds__(1024) void softmax_attn(float* __restrict__ logits) {
  float* base = logits + (size_t)blockIdx.x * 10000;
  float4* b4 = (float4*)base;
  const int t = threadIdx.x;
  const int lane = t & 63, w = t >> 6;
  __shared__ float red[32];

  float m = -3.0e38f;
  for (int i = t; i < 2500; i += 1024) {
    const float4 v = b4[i];
    m = fmaxf(m, fmaxf(fmaxf(v.x, v.y), fmaxf(v.z, v.w)));
  }
#pragma unroll
  for (int o = 32; o >= 1; o >>= 1) m = fmaxf(m, __shfl_xor(m, o));
  if (lane == 0) red[w] = m;
  __syncthreads();
#pragma unroll
  for (int i = 0; i < 16; ++i) m = fmaxf(m, red[i]);

  float s = 0.f;
  for (int i = t; i < 2500; i += 1024) {
    const float4 v = b4[i];
    s += __expf(v.x - m) + __expf(v.y - m) + __expf(v.z - m) + __expf(v.w - m);
  }
#pragma unroll
  for (int o = 32; o >= 1; o >>= 1) s += __shfl_xor(s, o);
  if (lane == 0) red[16 + w] = s;
  __syncthreads();
  s = 0.f;
#pragma unroll
  for (int i = 0; i < 16; ++i) s += red[16 + i];

  const float rs = 1.f / s;
  for (int i = t; i < 2500; i += 1024) {
    float4 v = b4[i];
    v.x = __expf(v.x - m) * rs;
    v.y = __expf(v.y - m) * rs;
    v.z = __expf(v.z - m) * rs;
    v.w = __expf(v.w - m) * rs;
    b4[i] = v;
  }
}

// ---------------------------------------------------------------------------
// scores[b,c] = sum_z reps[b,c,z] * Wcls[c,z], reps = sum_n attn[c,b,n]*emb[b,n,z].
// Shuffle-free main loop: lane owns z-slice [lane*8, lane*8+8); acc[c][j]
// accumulates attn-weighted emb. One dot+reduce per block at the end.
// grid (8 bags, 64 chunks of 157 rows), 256 threads (4 waves, row round-robin).
// ---------------------------------------------------------------------------
__global__ __launch_bounds__(256) void scores_partial(const bf16* __restrict__ emb,
                                                      const float* __restrict__ attn,
                                                      const float* __restrict__ Wcls,
                                                      float* __restrict__ sacc) {
  const int b = blockIdx.x;
  const int chunk = blockIdx.y;
  const int t = threadIdx.x;
  const int wave = t >> 6, lane = t & 63;

  float wcl[4][8];
#pragma unroll
  for (int c = 0; c < 4; ++c) {
    const float4 wlo = *(const float4*)(Wcls + c * 512 + lane * 8);
    const float4 whi = *(const float4*)(Wcls + c * 512 + lane * 8 + 4);
    wcl[c][0] = wlo.x; wcl[c][1] = wlo.y; wcl[c][2] = wlo.z; wcl[c][3] = wlo.w;
    wcl[c][4] = whi.x; wcl[c][5] = whi.y; wcl[c][6] = whi.z; wcl[c][7] = whi.w;
  }

  float acc[4][8];
#pragma unroll
  for (int c = 0; c < 4; ++c)
#pragma unroll
    for (int j = 0; j < 8; ++j) acc[c][j] = 0.f;

  const int nbeg = chunk * 157;
  const int nend = (nbeg + 157 < 10000) ? nbeg + 157 : 10000;
  for (int n = nbeg + wave; n < nend; n += 8) {
    // unroll-2: rows n and n+4 (this wave's next), loads issued up front
    const size_t row0 = (size_t)b * 10000 + n;
    const bf16x8 e0 = *(const bf16x8*)(emb + row0 * 512 + lane * 8);
    float w0[4];
#pragma unroll
    for (int c = 0; c < 4; ++c) w0[c] = attn[(size_t)c * 80000 + row0];
    const int n1 = n + 4;
    const bool v1 = (n1 < nend);
    bf16x8 e1;
    float w1[4];
    if (v1) {
      const size_t row1 = row0 + 4;
      e1 = *(const bf16x8*)(emb + row1 * 512 + lane * 8);
#pragma unroll
      for (int c = 0; c < 4; ++c) w1[c] = attn[(size_t)c * 80000 + row1];
    }
#pragma unroll
    for (int j = 0; j < 8; ++j) {
      const float e = (float)e0[j];
#pragma unroll
      for (int c = 0; c < 4; ++c) acc[c][j] += w0[c] * e;
    }
    if (v1) {
#pragma unroll
      for (int j = 0; j < 8; ++j) {
        const float e = (float)e1[j];
#pragma unroll
        for (int c = 0; c < 4; ++c) acc[c][j] += w1[c] * e;
      }
    }
  }

  // dot with Wcls, then ONE reduction per block
  float p[4];
#pragma unroll
  for (int c = 0; c < 4; ++c) {
    p[c] = 0.f;
#pragma unroll
    for (int j = 0; j < 8; ++j) p[c] += acc[c][j] * wcl[c][j];
  }
#pragma unroll
  for (int o = 32; o >= 1; o >>= 1) {
#pragma unroll
    for (int c = 0; c < 4; ++c) p[c] += __shfl_xor(p[c], o);
  }
  __shared__ float lred[4][4];
  if (lane == 0) {
#pragma unroll
    for (int c = 0; c < 4; ++c) lred[wave][c] = p[c];
  }
  __syncthreads();
  if (t < 4) {
    atomicAdd(&sacc[b * 4 + t], lred[0][t] + lred[1][t] + lred[2][t] + lred[3][t]);
  }
}

__global__ void finalize(const float* __restrict__ sacc, const float* __restrict__ b_cls,
                         float* __restrict__ out) {
  const int i = threadIdx.x;
  if (i < 32) out[i] = sacc[i] + b_cls[i & 3];
}

// ---------------------------------------------------------------------------
extern "C" void kernel_launch(void* const* d_in, const int* in_sizes, int n_in,
                              void* d_out, int out_size, void* d_ws, size_t ws_size,
                              hipStream_t stream) {
  (void)in_sizes; (void)n_in; (void)out_size; (void)ws_size;
  const float* bags   = (const float*)d_in[0];
  const float* W_enc  = (const float*)d_in[1];
  const float* b_enc  = (const float*)d_in[2];
  const float* W_u    = (const float*)d_in[3];
  const float* b_u    = (const float*)d_in[4];
  const float* W_v    = (const float*)d_in[5];
  const float* b_v    = (const float*)d_in[6];
  const float* W_attn = (const float*)d_in[7];
  // d_in[8] = b_attn: unused (cancels in softmax over instances)
  const float* W_cls  = (const float*)d_in[9];
  const float* b_cls  = (const float*)d_in[10];
  float* out = (float*)d_out;

  char* ws = (char*)d_ws;
  bf16*  emb     = (bf16*)(ws);                      // 80000*512*2  = 81,920,000 B
  float* logitsT = (float*)(ws + 81920000);          // 4*80000*4   =  1,280,000 B
  bf16*  WencT   = (bf16*)(ws + 83200000);           // 512*1024*2  =  1,048,576 B
  bf16*  WuT     = (bf16*)(ws + 84248576);           // 512*512*2   =    524,288 B
  bf16*  WvT     = (bf16*)(ws + 84772864);           // 512*512*2   =    524,288 B
  float* sacc    = (float*)(ws + 85297152);          // 32*4        =        128 B

  hipMemsetAsync(sacc, 0, 32 * sizeof(float), stream);

  transpose_cvt3<<<dim3(16, 32, 3), dim3(32, 8), 0, stream>>>(W_enc, W_u, W_v,
                                                              WencT, WuT, WvT);

  gemm_enc<<<1250, 512, 0, stream>>>(bags, WencT, b_enc, emb);
  gemm_gate<<<625, 512, 0, stream>>>(emb, WuT, WvT, b_u, b_v, W_attn, logitsT);
  softmax_attn<<<32, 1024, 0, stream>>>(logitsT);
  scores_partial<<<dim3(8, 64), 256, 0, stream>>>(emb, logitsT, W_cls, sacc);
  finalize<<<1, 64, 0, stream>>>(sacc, b_cls, out);
}